// Round 2
// baseline (780.493 us; speedup 1.0000x reference)
//
#include <hip/hip_runtime.h>

// Inputs/outputs are f32 (per reference setup_inputs). Compute in bf16 MFMA
// with f32 accumulation; intermediates stored bf16 in workspace.
// B=4, L=1024, D=1024, H=16, HD=64. M = B*L = 4096 tokens.

typedef __bf16 bf16;
typedef __attribute__((ext_vector_type(8))) __bf16 bf16x8;
typedef __attribute__((ext_vector_type(4))) float f32x4;

#define MFMA16(a, b, c) __builtin_amdgcn_mfma_f32_16x16x32_bf16((a), (b), (c), 0, 0, 0)

__device__ inline bf16x8 ld8(const bf16* p) { return *(const bf16x8*)p; }
__device__ inline bf16x8 ld8(const float* p) {
  bf16x8 r;
#pragma unroll
  for (int j = 0; j < 8; j++) r[j] = (bf16)p[j];
  return r;
}

// ---------------------------------------------------------------------------
// Weight transpose + f32->bf16 convert: in [R,C] f32 -> out [C,R] bf16
// ---------------------------------------------------------------------------
__global__ __launch_bounds__(256) void transpose_k(const float* __restrict__ in,
                                                   bf16* __restrict__ out,
                                                   int R, int C) {
  __shared__ bf16 tile[32][33];
  int c0 = blockIdx.x * 32, r0 = blockIdx.y * 32;
  int tx = threadIdx.x, ty = threadIdx.y;  // 32 x 8
#pragma unroll
  for (int i = 0; i < 32; i += 8)
    tile[ty + i][tx] = (bf16)in[(size_t)(r0 + ty + i) * C + c0 + tx];
  __syncthreads();
#pragma unroll
  for (int i = 0; i < 32; i += 8)
    out[(size_t)(c0 + ty + i) * R + r0 + tx] = tile[tx][ty + i];
}

// ---------------------------------------------------------------------------
// GEMM: C[m,n] = sum_k A[m,k]*W[k,n] + bias[n]; A cols 0..1023 from A0 (TA0),
// 1024.. from A1 (TA1). Wt = [N,K] bf16 (pre-transposed). M=4096, N=1024.
// 128x128 tile/block, 4 waves of 64x64.
// mode 0: out = acc+bias
// mode 1: g = sigmoid(acc+bias); out = g*enh + (1-g)*orig + orig  (LN input)
// mode 2: out = relu(acc+bias)
// ---------------------------------------------------------------------------
template <typename T>
__device__ inline void stageA(bf16* As, const T* Asrc, int m0, int tid) {
#pragma unroll
  for (int i = 0; i < 2; i++) {
    int c = tid + i * 256;         // 0..511
    int row = c >> 2, cc = c & 3;  // 128 rows x 4 chunks of 8
    *(bf16x8*)(As + row * 32 + cc * 8) =
        ld8(Asrc + (size_t)(m0 + row) * 1024 + cc * 8);
  }
}

template <typename TA0, typename TA1>
__global__ __launch_bounds__(256) void gemm128(
    const TA0* __restrict__ A0, const TA1* __restrict__ A1,
    const bf16* __restrict__ Wt, const float* __restrict__ bias,
    const float* __restrict__ orig, const bf16* __restrict__ enh,
    bf16* __restrict__ out, int K, int mode) {
  const int N = 1024;
  __shared__ bf16 As[128 * 32];
  __shared__ bf16 Bs[128 * 32];
  int tid = threadIdx.x;
  int m0 = blockIdx.y * 128, n0 = blockIdx.x * 128;
  int w = tid >> 6, lane = tid & 63, quad = lane >> 4, ln = lane & 15;
  int wm = (w >> 1) * 64, wn = (w & 1) * 64;

  const f32x4 z = {0.f, 0.f, 0.f, 0.f};
  f32x4 acc[4][4];
#pragma unroll
  for (int i = 0; i < 4; i++)
#pragma unroll
    for (int j = 0; j < 4; j++) acc[i][j] = z;

  for (int k0 = 0; k0 < K; k0 += 32) {
    __syncthreads();
    if (k0 < 1024)
      stageA(As, A0 + k0, m0, tid);
    else
      stageA(As, A1 + (k0 - 1024), m0, tid);
#pragma unroll
    for (int i = 0; i < 2; i++) {
      int c = tid + i * 256;
      int row = c >> 2, cc = c & 3;
      *(bf16x8*)(Bs + row * 32 + cc * 8) =
          *(const bf16x8*)(Wt + (size_t)(n0 + row) * K + k0 + cc * 8);
    }
    __syncthreads();

    bf16x8 af[4], bfv[4];
#pragma unroll
    for (int mt = 0; mt < 4; mt++)
      af[mt] = *(bf16x8*)(As + (wm + mt * 16 + ln) * 32 + quad * 8);
#pragma unroll
    for (int nt = 0; nt < 4; nt++)
      bfv[nt] = *(bf16x8*)(Bs + (wn + nt * 16 + ln) * 32 + quad * 8);
#pragma unroll
    for (int mt = 0; mt < 4; mt++)
#pragma unroll
      for (int nt = 0; nt < 4; nt++)
        acc[mt][nt] = MFMA16(af[mt], bfv[nt], acc[mt][nt]);
  }

#pragma unroll
  for (int nt = 0; nt < 4; nt++) {
    int n = n0 + wn + nt * 16 + ln;
    float bv = bias[n];
#pragma unroll
    for (int mt = 0; mt < 4; mt++) {
      int mb = m0 + wm + mt * 16 + quad * 4;
#pragma unroll
      for (int r = 0; r < 4; r++) {
        size_t idx = (size_t)(mb + r) * N + n;
        float v = acc[mt][nt][r] + bv;
        if (mode == 1) {
          float e = (float)enh[idx], o = orig[idx];
          float g = 1.f / (1.f + __expf(-v));
          v = g * e + (1.f - g) * o + o;  // gate fusion + residual
        } else if (mode == 2) {
          v = fmaxf(v, 0.f);
        }
        out[idx] = (bf16)v;
      }
    }
  }
}

// ---------------------------------------------------------------------------
// Flash attention: one block = (b, h, 64 q-rows); 4 waves x 16 q-rows.
// scores = Q K^T / 8, online softmax, O = P V.  L=1024, HD=64. All bf16 I/O.
// ---------------------------------------------------------------------------
__global__ __launch_bounds__(256) void attn_k(const bf16* __restrict__ Q,
                                              const bf16* __restrict__ Kp,
                                              const bf16* __restrict__ Vp,
                                              bf16* __restrict__ O) {
  const int D = 1024, L = 1024;
  int blk = blockIdx.x;
  int qblk = blk & 15, bh = blk >> 4;
  int h = bh & 15, b = bh >> 4;
  size_t base = ((size_t)b * L) * D + h * 64;

  __shared__ bf16 Kt[64 * 64];     // [k][d]
  __shared__ bf16 Vt[64 * 64];     // [k][d]
  __shared__ bf16 Pw[4][16 * 64];  // per-wave P tile [q][k]

  int tid = threadIdx.x, w = tid >> 6, lane = tid & 63;
  int quad = lane >> 4, ln = lane & 15;
  int q0 = qblk * 64 + w * 16;

  bf16x8 qf0 = *(const bf16x8*)(Q + base + (size_t)(q0 + ln) * D + quad * 8);
  bf16x8 qf1 = *(const bf16x8*)(Q + base + (size_t)(q0 + ln) * D + quad * 8 + 32);

  const f32x4 z = {0.f, 0.f, 0.f, 0.f};
  f32x4 oacc[4];
#pragma unroll
  for (int i = 0; i < 4; i++) oacc[i] = z;
  float m_run[4], l_run[4];
#pragma unroll
  for (int r = 0; r < 4; r++) { m_run[r] = -1e30f; l_run[r] = 0.f; }

  for (int kv0 = 0; kv0 < L; kv0 += 64) {
    __syncthreads();
#pragma unroll
    for (int i = 0; i < 2; i++) {
      int c = tid + i * 256;
      int row = c >> 3, ch = c & 7;
      size_t g = base + (size_t)(kv0 + row) * D + ch * 8;
      *(bf16x8*)(Kt + row * 64 + ch * 8) = *(const bf16x8*)(Kp + g);
      *(bf16x8*)(Vt + row * 64 + ch * 8) = *(const bf16x8*)(Vp + g);
    }
    __syncthreads();

    f32x4 s[4];
#pragma unroll
    for (int nt = 0; nt < 4; nt++) {
      bf16x8 k0f = *(bf16x8*)(Kt + (nt * 16 + ln) * 64 + quad * 8);
      bf16x8 k1f = *(bf16x8*)(Kt + (nt * 16 + ln) * 64 + quad * 8 + 32);
      f32x4 a = z;
      a = MFMA16(qf0, k0f, a);
      a = MFMA16(qf1, k1f, a);
      s[nt] = a * 0.125f;  // 1/sqrt(64)
    }

    float mx[4];
#pragma unroll
    for (int r = 0; r < 4; r++)
      mx[r] = fmaxf(fmaxf(s[0][r], s[1][r]), fmaxf(s[2][r], s[3][r]));
#pragma unroll
    for (int msk = 1; msk < 16; msk <<= 1)
#pragma unroll
      for (int r = 0; r < 4; r++) mx[r] = fmaxf(mx[r], __shfl_xor(mx[r], msk, 64));

    float alpha[4];
#pragma unroll
    for (int r = 0; r < 4; r++) {
      float mn = fmaxf(m_run[r], mx[r]);
      alpha[r] = __expf(m_run[r] - mn);
      m_run[r] = mn;
    }
    float rs[4] = {0.f, 0.f, 0.f, 0.f};
#pragma unroll
    for (int nt = 0; nt < 4; nt++)
#pragma unroll
      for (int r = 0; r < 4; r++) {
        float p = __expf(s[nt][r] - m_run[r]);
        s[nt][r] = p;
        rs[r] += p;
      }
#pragma unroll
    for (int msk = 1; msk < 16; msk <<= 1)
#pragma unroll
      for (int r = 0; r < 4; r++) rs[r] += __shfl_xor(rs[r], msk, 64);
#pragma unroll
    for (int r = 0; r < 4; r++) l_run[r] = l_run[r] * alpha[r] + rs[r];
#pragma unroll
    for (int dt = 0; dt < 4; dt++)
#pragma unroll
      for (int r = 0; r < 4; r++) oacc[dt][r] *= alpha[r];

#pragma unroll
    for (int nt = 0; nt < 4; nt++)
#pragma unroll
      for (int r = 0; r < 4; r++)
        Pw[w][(quad * 4 + r) * 64 + nt * 16 + ln] = (bf16)s[nt][r];
    __syncthreads();

    bf16x8 pa0 = *(bf16x8*)(Pw[w] + ln * 64 + quad * 8);
    bf16x8 pa1 = *(bf16x8*)(Pw[w] + ln * 64 + quad * 8 + 32);
#pragma unroll
    for (int dt = 0; dt < 4; dt++) {
      bf16x8 vb0, vb1;
#pragma unroll
      for (int j = 0; j < 8; j++) {
        vb0[j] = Vt[(quad * 8 + j) * 64 + dt * 16 + ln];
        vb1[j] = Vt[(quad * 8 + j + 32) * 64 + dt * 16 + ln];
      }
      oacc[dt] = MFMA16(pa0, vb0, oacc[dt]);
      oacc[dt] = MFMA16(pa1, vb1, oacc[dt]);
    }
  }

#pragma unroll
  for (int dt = 0; dt < 4; dt++)
#pragma unroll
    for (int r = 0; r < 4; r++) {
      int q = q0 + quad * 4 + r;
      float v = oacc[dt][r] / l_run[r];
      O[base + (size_t)q * D + dt * 16 + ln] = (bf16)v;
    }
}

// ---------------------------------------------------------------------------
// LayerNorm over D=1024, one block per row. x bf16, gamma/beta f32, y bf16.
// ---------------------------------------------------------------------------
__global__ __launch_bounds__(256) void ln_k(const bf16* __restrict__ x,
                                            const float* __restrict__ gg,
                                            const float* __restrict__ bb,
                                            bf16* __restrict__ y) {
  int row = blockIdx.x, tid = threadIdx.x;
  const bf16* xr = x + (size_t)row * 1024;
  float v[4], s = 0.f, ss = 0.f;
#pragma unroll
  for (int i = 0; i < 4; i++) {
    v[i] = (float)xr[tid + i * 256];
    s += v[i];
    ss += v[i] * v[i];
  }
#pragma unroll
  for (int o = 32; o > 0; o >>= 1) {
    s += __shfl_down(s, o, 64);
    ss += __shfl_down(ss, o, 64);
  }
  __shared__ float red[8];
  int w = tid >> 6;
  if ((tid & 63) == 0) { red[w] = s; red[4 + w] = ss; }
  __syncthreads();
  s = red[0] + red[1] + red[2] + red[3];
  ss = red[4] + red[5] + red[6] + red[7];
  float mu = s * (1.f / 1024.f);
  float var = ss * (1.f / 1024.f) - mu * mu;
  float rstd = rsqrtf(var + 1e-5f);
#pragma unroll
  for (int i = 0; i < 4; i++) {
    int c = tid + i * 256;
    y[(size_t)row * 1024 + c] = (bf16)((v[i] - mu) * rstd * gg[c] + bb[c]);
  }
}

// ---------------------------------------------------------------------------
// fw = sigmoid(t . fg2_w + fg2_b); out = fw*hbp + (1-fw)*hpp  (block per row)
// t/hbp/hpp bf16, fg2_w/fg2_b f32, out f32.
// ---------------------------------------------------------------------------
__global__ __launch_bounds__(256) void fg2mix_k(const bf16* __restrict__ t,
                                                const float* __restrict__ w2,
                                                const float* __restrict__ b2,
                                                const bf16* __restrict__ hbp,
                                                const bf16* __restrict__ hpp,
                                                float* __restrict__ out) {
  int row = blockIdx.x, tid = threadIdx.x;
  float s = 0.f;
#pragma unroll
  for (int i = 0; i < 4; i++) {
    int c = tid + i * 256;
    s += (float)t[(size_t)row * 1024 + c] * w2[c];
  }
#pragma unroll
  for (int o = 32; o > 0; o >>= 1) s += __shfl_down(s, o, 64);
  __shared__ float red[4];
  if ((tid & 63) == 0) red[tid >> 6] = s;
  __syncthreads();
  s = red[0] + red[1] + red[2] + red[3];
  float fw = 1.f / (1.f + __expf(-(s + b2[0])));
#pragma unroll
  for (int i = 0; i < 4; i++) {
    size_t idx = (size_t)row * 1024 + tid + i * 256;
    out[idx] = fw * (float)hbp[idx] + (1.f - fw) * (float)hpp[idx];
  }
}

// ---------------------------------------------------------------------------
extern "C" void kernel_launch(void* const* d_in, const int* in_sizes, int n_in,
                              void* d_out, int out_size, void* d_ws,
                              size_t ws_size, hipStream_t stream) {
  const float* h_b     = (const float*)d_in[0];
  const float* h_p     = (const float*)d_in[1];
  const float* wq      = (const float*)d_in[2];
  const float* bq      = (const float*)d_in[3];
  const float* wk_sem  = (const float*)d_in[4];
  const float* bk_sem  = (const float*)d_in[5];
  const float* wk_syn  = (const float*)d_in[6];
  const float* bk_syn  = (const float*)d_in[7];
  const float* wv      = (const float*)d_in[8];
  const float* bv      = (const float*)d_in[9];
  const float* g_sem_w = (const float*)d_in[10];
  const float* g_sem_b = (const float*)d_in[11];
  const float* g_syn_w = (const float*)d_in[12];
  const float* g_syn_b = (const float*)d_in[13];
  const float* ln_sem_g = (const float*)d_in[14];
  const float* ln_sem_b = (const float*)d_in[15];
  const float* ln_syn_g = (const float*)d_in[16];
  const float* ln_syn_b = (const float*)d_in[17];
  const float* fg1_w   = (const float*)d_in[18];
  const float* fg1_b   = (const float*)d_in[19];
  const float* fg2_w   = (const float*)d_in[20];
  const float* fg2_b   = (const float*)d_in[21];

  // workspace (bf16 elements). Layout in units of 1M bf16 (2MB):
  // total 30M bf16 = 60 MB.
  bf16* ws = (bf16*)d_ws;
  const size_t M1 = 1024ull * 1024ull;
  bf16* wqT    = ws + 0 * M1;   // [1024,1024] each
  bf16* wkSemT = ws + 1 * M1;
  bf16* wkSynT = ws + 2 * M1;
  bf16* wvT    = ws + 3 * M1;
  bf16* gSemT  = ws + 4 * M1;   // [1024,2048] each
  bf16* gSynT  = ws + 6 * M1;
  bf16* fg1T   = ws + 8 * M1;
  bf16* qb  = ws + 10 * M1;     // [4096,1024] each
  bf16* kb  = ws + 14 * M1;
  bf16* vb  = ws + 18 * M1;
  bf16* e0b = ws + 22 * M1;
  bf16* e1b = ws + 26 * M1;
  // aliases over dead buffers
  bf16* ln0 = qb;
  bf16* ln1 = kb;
  bf16* hbp = vb;
  bf16* hpp = e0b;   // e0b dead after gate gemm 0
  bf16* tb  = e1b;   // e1b dead after gate gemm 1

  dim3 tpb(32, 8);
  transpose_k<<<dim3(32, 32), tpb, 0, stream>>>(wq, wqT, 1024, 1024);
  transpose_k<<<dim3(32, 32), tpb, 0, stream>>>(wk_sem, wkSemT, 1024, 1024);
  transpose_k<<<dim3(32, 32), tpb, 0, stream>>>(wk_syn, wkSynT, 1024, 1024);
  transpose_k<<<dim3(32, 32), tpb, 0, stream>>>(wv, wvT, 1024, 1024);
  transpose_k<<<dim3(32, 64), tpb, 0, stream>>>(g_sem_w, gSemT, 2048, 1024);
  transpose_k<<<dim3(32, 64), tpb, 0, stream>>>(g_syn_w, gSynT, 2048, 1024);
  transpose_k<<<dim3(32, 64), tpb, 0, stream>>>(fg1_w, fg1T, 2048, 1024);

  dim3 gg(8, 32);  // N/128, M/128

  // branch 0 (semantic): q=h_b@wq, k=h_p@wk_syn, v=h_p@wv
  gemm128<float, float><<<gg, 256, 0, stream>>>(h_b, nullptr, wqT, bq, nullptr, nullptr, qb, 1024, 0);
  gemm128<float, float><<<gg, 256, 0, stream>>>(h_p, nullptr, wkSynT, bk_syn, nullptr, nullptr, kb, 1024, 0);
  gemm128<float, float><<<gg, 256, 0, stream>>>(h_p, nullptr, wvT, bv, nullptr, nullptr, vb, 1024, 0);
  attn_k<<<1024, 256, 0, stream>>>(qb, kb, vb, e0b);

  // branch 1 (syntax): q=h_p@wq, k=h_b@wk_sem, v=h_b@wv  (reuse qb/kb/vb)
  gemm128<float, float><<<gg, 256, 0, stream>>>(h_p, nullptr, wqT, bq, nullptr, nullptr, qb, 1024, 0);
  gemm128<float, float><<<gg, 256, 0, stream>>>(h_b, nullptr, wkSemT, bk_sem, nullptr, nullptr, kb, 1024, 0);
  gemm128<float, float><<<gg, 256, 0, stream>>>(h_b, nullptr, wvT, bv, nullptr, nullptr, vb, 1024, 0);
  attn_k<<<1024, 256, 0, stream>>>(qb, kb, vb, e1b);

  // gate fusion (+ residual) -> LN input
  gemm128<float, bf16><<<gg, 256, 0, stream>>>(h_b, e0b, gSemT, g_sem_b, h_b, e0b, ln0, 2048, 1);
  gemm128<float, bf16><<<gg, 256, 0, stream>>>(h_p, e1b, gSynT, g_syn_b, h_p, e1b, ln1, 2048, 1);

  ln_k<<<4096, 256, 0, stream>>>(ln0, ln_sem_g, ln_sem_b, hbp);
  ln_k<<<4096, 256, 0, stream>>>(ln1, ln_syn_g, ln_syn_b, hpp);

  // fg1: relu(cat[hbp,hpp] @ fg1_w + b)
  gemm128<bf16, bf16><<<gg, 256, 0, stream>>>(hbp, hpp, fg1T, fg1_b, nullptr, nullptr, tb, 2048, 2);

  fg2mix_k<<<4096, 256, 0, stream>>>(tb, fg2_w, fg2_b, hbp, hpp, (float*)d_out);
}

// Round 3
// 738.337 us; speedup vs baseline: 1.0571x; 1.0571x over previous
//
#include <hip/hip_runtime.h>

// Inputs/outputs f32; compute bf16 MFMA with f32 accumulation.
// B=4, L=1024, D=1024, H=16, HD=64. M = 4096 tokens.

typedef __bf16 bf16;
typedef __attribute__((ext_vector_type(4))) __bf16 bf16x4;
typedef __attribute__((ext_vector_type(8))) __bf16 bf16x8;
typedef __attribute__((ext_vector_type(4))) float f32x4;

#define MFMA16(a, b, c) __builtin_amdgcn_mfma_f32_16x16x32_bf16((a), (b), (c), 0, 0, 0)

// async global->LDS, 16B per lane; lds dest = wave-uniform base + lane*16
__device__ inline void async16(const bf16* g, bf16* l) {
  __builtin_amdgcn_global_load_lds(
      (const __attribute__((address_space(1))) unsigned int*)g,
      (__attribute__((address_space(3))) unsigned int*)l, 16, 0, 0);
}

// ---------------------------------------------------------------------------
// Weight transpose + f32->bf16: in [R,C] f32 -> out [C,R] bf16
// ---------------------------------------------------------------------------
__global__ __launch_bounds__(256) void transpose_k(const float* __restrict__ in,
                                                   bf16* __restrict__ out,
                                                   int R, int C) {
  __shared__ bf16 tile[32][33];
  int c0 = blockIdx.x * 32, r0 = blockIdx.y * 32;
  int tx = threadIdx.x, ty = threadIdx.y;  // 32 x 8
#pragma unroll
  for (int i = 0; i < 32; i += 8)
    tile[ty + i][tx] = (bf16)in[(size_t)(r0 + ty + i) * C + c0 + tx];
  __syncthreads();
#pragma unroll
  for (int i = 0; i < 32; i += 8)
    out[(size_t)(c0 + ty + i) * R + r0 + tx] = tile[tx][ty + i];
}

// ---------------------------------------------------------------------------
// GEMM 128x128 tile, 4 waves x 64x64. Wt = [N=1024][K] bf16.
// A cols 0..1023 from A0, 1024.. from A1 (both row-stride 1024).
// mode 0: out[m][n] = acc+bias            (out stride 1024)
// mode 1: g=sigmoid(acc+bias); out = g*enh+(1-g)*orig+orig
// mode 2: out = relu(acc+bias)
// mode 3: out[n][m] = acc+bias transposed (out stride 4096)
// ---------------------------------------------------------------------------
__device__ inline void stageA(bf16* As, const float* Asrc, int m0, int tid) {
#pragma unroll
  for (int i = 0; i < 2; i++) {
    int s = tid + i * 256;
    int row = s >> 2, ch = s & 3;
    const float* p = Asrc + (size_t)(m0 + row) * 1024 + ch * 8;
    f32x4 x = *(const f32x4*)p, y = *(const f32x4*)(p + 4);
    bf16x8 r;
#pragma unroll
    for (int j = 0; j < 4; j++) { r[j] = (bf16)x[j]; r[4 + j] = (bf16)y[j]; }
    *(bf16x8*)(As + s * 8) = r;
  }
}
__device__ inline void stageA(bf16* As, const bf16* Asrc, int m0, int tid) {
#pragma unroll
  for (int i = 0; i < 2; i++) {
    int s = tid + i * 256;
    int row = s >> 2, ch = s & 3;
    async16(Asrc + (size_t)(m0 + row) * 1024 + ch * 8,
            As + ((size_t)(i * 256 + (tid & ~63))) * 8);
  }
}

template <typename TA0, typename TA1>
__global__ __launch_bounds__(256) void gemm128(
    const TA0* __restrict__ A0, const TA1* __restrict__ A1,
    const bf16* __restrict__ Wt, const float* __restrict__ bias,
    const float* __restrict__ orig, const bf16* __restrict__ enh,
    bf16* __restrict__ out, int K, int mode) {
  __shared__ bf16 As[128 * 32];
  __shared__ bf16 Bs[128 * 32];
  int tid = threadIdx.x;
  int m0 = blockIdx.y * 128, n0 = blockIdx.x * 128;
  int w = tid >> 6, lane = tid & 63, quad = lane >> 4, ln = lane & 15;
  int wm = (w >> 1) * 64, wn = (w & 1) * 64;

  const f32x4 z = {0.f, 0.f, 0.f, 0.f};
  f32x4 acc[4][4];
#pragma unroll
  for (int i = 0; i < 4; i++)
#pragma unroll
    for (int j = 0; j < 4; j++) acc[i][j] = z;

  for (int k0 = 0; k0 < K; k0 += 32) {
    __syncthreads();
    // B tile: async direct-to-LDS
#pragma unroll
    for (int i = 0; i < 2; i++) {
      int s = tid + i * 256;
      int row = s >> 2, ch = s & 3;
      async16(Wt + (size_t)(n0 + row) * K + k0 + ch * 8,
              Bs + ((size_t)(i * 256 + (tid & ~63))) * 8);
    }
    if (k0 < 1024)
      stageA(As, A0 + k0, m0, tid);
    else
      stageA(As, A1 + (k0 - 1024), m0, tid);
    __syncthreads();

    bf16x8 af[4], bfv[4];
#pragma unroll
    for (int mt = 0; mt < 4; mt++)
      af[mt] = *(bf16x8*)(As + (wm + mt * 16 + ln) * 32 + quad * 8);
#pragma unroll
    for (int nt = 0; nt < 4; nt++)
      bfv[nt] = *(bf16x8*)(Bs + (wn + nt * 16 + ln) * 32 + quad * 8);
#pragma unroll
    for (int mt = 0; mt < 4; mt++)
#pragma unroll
      for (int nt = 0; nt < 4; nt++)
        acc[mt][nt] = MFMA16(af[mt], bfv[nt], acc[mt][nt]);
  }

  if (mode == 3) {
#pragma unroll
    for (int nt = 0; nt < 4; nt++) {
      int n = n0 + wn + nt * 16 + ln;
      float bv = bias[n];
#pragma unroll
      for (int mt = 0; mt < 4; mt++) {
        int mb = m0 + wm + mt * 16 + quad * 4;
        bf16x4 pk;
#pragma unroll
        for (int r = 0; r < 4; r++) pk[r] = (bf16)(acc[mt][nt][r] + bv);
        *(bf16x4*)(out + (size_t)n * 4096 + mb) = pk;
      }
    }
    return;
  }
#pragma unroll
  for (int nt = 0; nt < 4; nt++) {
    int n = n0 + wn + nt * 16 + ln;
    float bv = bias[n];
#pragma unroll
    for (int mt = 0; mt < 4; mt++) {
      int mb = m0 + wm + mt * 16 + quad * 4;
#pragma unroll
      for (int r = 0; r < 4; r++) {
        size_t idx = (size_t)(mb + r) * 1024 + n;
        float v = acc[mt][nt][r] + bv;
        if (mode == 1) {
          float e = (float)enh[idx], o = orig[idx];
          float g = 1.f / (1.f + __expf(-v));
          v = g * e + (1.f - g) * o + o;  // gate fusion + residual
        } else if (mode == 2) {
          v = fmaxf(v, 0.f);
        }
        out[idx] = (bf16)v;
      }
    }
  }
}

// ---------------------------------------------------------------------------
// Flash attention. One block = (b, h, 128 q rows); 4 waves x 32 q rows.
// Q,K: [4096 tok][1024] bf16 (head slice h*64). Vt: [1024 d][4096 tok] bf16.
// LDS tiles in split-half layout (row stride 32 el) for clean b128 reads.
// ---------------------------------------------------------------------------
__global__ __launch_bounds__(256) void attn_k(const bf16* __restrict__ Q,
                                              const bf16* __restrict__ Kp,
                                              const bf16* __restrict__ Vg,
                                              bf16* __restrict__ O) {
  int blk = blockIdx.x;
  int qblk = blk & 7, bh = blk >> 3;
  int h = bh & 15, b = bh >> 4;
  size_t kbase = ((size_t)b * 1024) * 1024 + h * 64;  // [tok][1024] + head col
  size_t vbase = (size_t)h * 64 * 4096 + b * 1024;    // [d][4096] + batch col

  __shared__ bf16 Kt[2 * 64 * 32];   // [dhalf][k][32]
  __shared__ bf16 Vt[2 * 64 * 32];   // [khalf][d][32]
  __shared__ bf16 Pw[4][2 * 32 * 32];  // per wave: [khalf][q][32]

  int tid = threadIdx.x, w = tid >> 6, lane = tid & 63;
  int quad = lane >> 4, ln = lane & 15;
  int wq0 = qblk * 128 + w * 32;

  // Q fragments: A[m=ln][kd = half*32 + quad*8 + j]
  bf16x8 qf[2][2];
#pragma unroll
  for (int mt = 0; mt < 2; mt++)
#pragma unroll
    for (int hf = 0; hf < 2; hf++)
      qf[mt][hf] = *(const bf16x8*)(Q + kbase +
          (size_t)(wq0 + mt * 16 + ln) * 1024 + hf * 32 + quad * 8);

  const f32x4 z = {0.f, 0.f, 0.f, 0.f};
  f32x4 oacc[2][4];
#pragma unroll
  for (int mt = 0; mt < 2; mt++)
#pragma unroll
    for (int dt = 0; dt < 4; dt++) oacc[mt][dt] = z;
  float m_run[2][4], l_run[2][4];
#pragma unroll
  for (int mt = 0; mt < 2; mt++)
#pragma unroll
    for (int r = 0; r < 4; r++) { m_run[mt][r] = -1e30f; l_run[mt][r] = 0.f; }

  for (int kv0 = 0; kv0 < 1024; kv0 += 64) {
    __syncthreads();  // previous tile fully consumed
#pragma unroll
    for (int i = 0; i < 2; i++) {
      int s = tid + i * 256;       // slot: half=s>>8, row=(s>>2)&63, ch=s&3
      bf16* ldst = (bf16*)0;
      size_t wb = (size_t)(i * 256 + (tid & ~63)) * 8;
      // K: LDS [dhalf][k][32]
      async16(Kp + kbase + (size_t)(kv0 + ((s >> 2) & 63)) * 1024 +
                  (s >> 8) * 32 + (s & 3) * 8,
              Kt + wb);
      // V: LDS [khalf][d][32]
      async16(Vg + vbase + (size_t)((s >> 2) & 63) * 4096 + kv0 +
                  (s >> 8) * 32 + (s & 3) * 8,
              Vt + wb);
      (void)ldst;
    }
    __syncthreads();

    // K fragments: B[n=k-token][kd]: Kt[half][nt*16+ln][quad*8..]
    bf16x8 kf[4][2];
#pragma unroll
    for (int nt = 0; nt < 4; nt++)
#pragma unroll
      for (int hf = 0; hf < 2; hf++)
        kf[nt][hf] = *(bf16x8*)(Kt + hf * 2048 + (nt * 16 + ln) * 32 + quad * 8);

    f32x4 s[2][4];
#pragma unroll
    for (int mt = 0; mt < 2; mt++)
#pragma unroll
      for (int nt = 0; nt < 4; nt++) {
        f32x4 a = z;
        a = MFMA16(qf[mt][0], kf[nt][0], a);
        a = MFMA16(qf[mt][1], kf[nt][1], a);
        s[mt][nt] = a * 0.125f;  // 1/sqrt(64)
      }

#pragma unroll
    for (int mt = 0; mt < 2; mt++) {
      float mx[4];
#pragma unroll
      for (int r = 0; r < 4; r++)
        mx[r] = fmaxf(fmaxf(s[mt][0][r], s[mt][1][r]),
                      fmaxf(s[mt][2][r], s[mt][3][r]));
#pragma unroll
      for (int msk = 1; msk < 16; msk <<= 1)
#pragma unroll
        for (int r = 0; r < 4; r++)
          mx[r] = fmaxf(mx[r], __shfl_xor(mx[r], msk, 64));
      float alpha[4];
#pragma unroll
      for (int r = 0; r < 4; r++) {
        float mn = fmaxf(m_run[mt][r], mx[r]);
        alpha[r] = __expf(m_run[mt][r] - mn);
        m_run[mt][r] = mn;
      }
      float rs[4] = {0.f, 0.f, 0.f, 0.f};
#pragma unroll
      for (int nt = 0; nt < 4; nt++)
#pragma unroll
        for (int r = 0; r < 4; r++) {
          float p = __expf(s[mt][nt][r] - m_run[mt][r]);
          s[mt][nt][r] = p;
          rs[r] += p;
        }
#pragma unroll
      for (int msk = 1; msk < 16; msk <<= 1)
#pragma unroll
        for (int r = 0; r < 4; r++) rs[r] += __shfl_xor(rs[r], msk, 64);
#pragma unroll
      for (int r = 0; r < 4; r++)
        l_run[mt][r] = l_run[mt][r] * alpha[r] + rs[r];
#pragma unroll
      for (int dt = 0; dt < 4; dt++)
#pragma unroll
        for (int r = 0; r < 4; r++) oacc[mt][dt][r] *= alpha[r];

      // P: C-layout -> per-wave LDS [khalf][q][32] (wave-local, no barrier)
#pragma unroll
      for (int nt = 0; nt < 4; nt++)
#pragma unroll
        for (int r = 0; r < 4; r++)
          Pw[w][(nt >> 1) * 1024 + (mt * 16 + quad * 4 + r) * 32 +
                (nt & 1) * 16 + ln] = (bf16)s[mt][nt][r];
    }

    bf16x8 pa[2][2];
#pragma unroll
    for (int mt = 0; mt < 2; mt++)
#pragma unroll
      for (int hf = 0; hf < 2; hf++)
        pa[mt][hf] =
            *(bf16x8*)(Pw[w] + hf * 1024 + (mt * 16 + ln) * 32 + quad * 8);

#pragma unroll
    for (int dt = 0; dt < 4; dt++) {
      bf16x8 vb0 = *(bf16x8*)(Vt + (dt * 16 + ln) * 32 + quad * 8);
      bf16x8 vb1 = *(bf16x8*)(Vt + 2048 + (dt * 16 + ln) * 32 + quad * 8);
#pragma unroll
      for (int mt = 0; mt < 2; mt++) {
        oacc[mt][dt] = MFMA16(pa[mt][0], vb0, oacc[mt][dt]);
        oacc[mt][dt] = MFMA16(pa[mt][1], vb1, oacc[mt][dt]);
      }
    }
  }

#pragma unroll
  for (int mt = 0; mt < 2; mt++)
#pragma unroll
    for (int dt = 0; dt < 4; dt++)
#pragma unroll
      for (int r = 0; r < 4; r++) {
        int q = wq0 + mt * 16 + quad * 4 + r;
        O[kbase + (size_t)q * 1024 + dt * 16 + ln] =
            (bf16)(oacc[mt][dt][r] / l_run[mt][r]);
      }
}

// ---------------------------------------------------------------------------
// LayerNorm over D=1024, one block per row, vectorized x4.
// ---------------------------------------------------------------------------
__global__ __launch_bounds__(256) void ln_k(const bf16* __restrict__ x,
                                            const float* __restrict__ gg,
                                            const float* __restrict__ bb,
                                            bf16* __restrict__ y) {
  int row = blockIdx.x, tid = threadIdx.x, c = tid * 4;
  const bf16* xr = x + (size_t)row * 1024;
  bf16x4 x4 = *(const bf16x4*)(xr + c);
  float v[4], s = 0.f, ss = 0.f;
#pragma unroll
  for (int i = 0; i < 4; i++) {
    v[i] = (float)x4[i];
    s += v[i];
    ss += v[i] * v[i];
  }
#pragma unroll
  for (int o = 32; o > 0; o >>= 1) {
    s += __shfl_down(s, o, 64);
    ss += __shfl_down(ss, o, 64);
  }
  __shared__ float red[8];
  int w = tid >> 6;
  if ((tid & 63) == 0) { red[w] = s; red[4 + w] = ss; }
  __syncthreads();
  s = red[0] + red[1] + red[2] + red[3];
  ss = red[4] + red[5] + red[6] + red[7];
  float mu = s * (1.f / 1024.f);
  float var = ss * (1.f / 1024.f) - mu * mu;
  float rstd = rsqrtf(var + 1e-5f);
  f32x4 g4 = *(const f32x4*)(gg + c), b4 = *(const f32x4*)(bb + c);
  bf16x4 o4;
#pragma unroll
  for (int i = 0; i < 4; i++) o4[i] = (bf16)((v[i] - mu) * rstd * g4[i] + b4[i]);
  *(bf16x4*)(y + (size_t)row * 1024 + c) = o4;
}

// ---------------------------------------------------------------------------
// fw = sigmoid(t . w2 + b2); out = fw*hbp + (1-fw)*hpp  (block per row)
// ---------------------------------------------------------------------------
__global__ __launch_bounds__(256) void fg2mix_k(const bf16* __restrict__ t,
                                                const float* __restrict__ w2,
                                                const float* __restrict__ b2,
                                                const bf16* __restrict__ hbp,
                                                const bf16* __restrict__ hpp,
                                                float* __restrict__ out) {
  int row = blockIdx.x, tid = threadIdx.x, c = tid * 4;
  bf16x4 t4 = *(const bf16x4*)(t + (size_t)row * 1024 + c);
  f32x4 w4 = *(const f32x4*)(w2 + c);
  float s = 0.f;
#pragma unroll
  for (int i = 0; i < 4; i++) s += (float)t4[i] * w4[i];
#pragma unroll
  for (int o = 32; o > 0; o >>= 1) s += __shfl_down(s, o, 64);
  __shared__ float red[4];
  if ((tid & 63) == 0) red[tid >> 6] = s;
  __syncthreads();
  s = red[0] + red[1] + red[2] + red[3];
  float fw = 1.f / (1.f + __expf(-(s + b2[0])));
  bf16x4 a4 = *(const bf16x4*)(hbp + (size_t)row * 1024 + c);
  bf16x4 p4 = *(const bf16x4*)(hpp + (size_t)row * 1024 + c);
  f32x4 o4;
#pragma unroll
  for (int i = 0; i < 4; i++) o4[i] = fw * (float)a4[i] + (1.f - fw) * (float)p4[i];
  *(f32x4*)(out + (size_t)row * 1024 + c) = o4;
}

// ---------------------------------------------------------------------------
extern "C" void kernel_launch(void* const* d_in, const int* in_sizes, int n_in,
                              void* d_out, int out_size, void* d_ws,
                              size_t ws_size, hipStream_t stream) {
  const float* h_b     = (const float*)d_in[0];
  const float* h_p     = (const float*)d_in[1];
  const float* wq      = (const float*)d_in[2];
  const float* bq      = (const float*)d_in[3];
  const float* wk_sem  = (const float*)d_in[4];
  const float* bk_sem  = (const float*)d_in[5];
  const float* wk_syn  = (const float*)d_in[6];
  const float* bk_syn  = (const float*)d_in[7];
  const float* wv      = (const float*)d_in[8];
  const float* bv      = (const float*)d_in[9];
  const float* g_sem_w = (const float*)d_in[10];
  const float* g_sem_b = (const float*)d_in[11];
  const float* g_syn_w = (const float*)d_in[12];
  const float* g_syn_b = (const float*)d_in[13];
  const float* ln_sem_g = (const float*)d_in[14];
  const float* ln_sem_b = (const float*)d_in[15];
  const float* ln_syn_g = (const float*)d_in[16];
  const float* ln_syn_b = (const float*)d_in[17];
  const float* fg1_w   = (const float*)d_in[18];
  const float* fg1_b   = (const float*)d_in[19];
  const float* fg2_w   = (const float*)d_in[20];
  const float* fg2_b   = (const float*)d_in[21];

  // workspace: 30M bf16 = 60 MB
  bf16* ws = (bf16*)d_ws;
  const size_t M1 = 1024ull * 1024ull;
  bf16* wqT    = ws + 0 * M1;
  bf16* wkSemT = ws + 1 * M1;
  bf16* wkSynT = ws + 2 * M1;
  bf16* wvT    = ws + 3 * M1;
  bf16* gSemT  = ws + 4 * M1;
  bf16* gSynT  = ws + 6 * M1;
  bf16* fg1T   = ws + 8 * M1;
  bf16* qb  = ws + 10 * M1;   // [4096][1024]
  bf16* kb  = ws + 14 * M1;   // [4096][1024]
  bf16* vtb = ws + 18 * M1;   // [1024][4096]  (V transposed)
  bf16* e0b = ws + 22 * M1;
  bf16* e1b = ws + 26 * M1;
  bf16* ln0 = qb;
  bf16* ln1 = kb;
  bf16* hbp = vtb;
  bf16* hpp = e0b;
  bf16* tb  = e1b;

  dim3 tpb(32, 8);
  transpose_k<<<dim3(32, 32), tpb, 0, stream>>>(wq, wqT, 1024, 1024);
  transpose_k<<<dim3(32, 32), tpb, 0, stream>>>(wk_sem, wkSemT, 1024, 1024);
  transpose_k<<<dim3(32, 32), tpb, 0, stream>>>(wk_syn, wkSynT, 1024, 1024);
  transpose_k<<<dim3(32, 32), tpb, 0, stream>>>(wv, wvT, 1024, 1024);
  transpose_k<<<dim3(32, 64), tpb, 0, stream>>>(g_sem_w, gSemT, 2048, 1024);
  transpose_k<<<dim3(32, 64), tpb, 0, stream>>>(g_syn_w, gSynT, 2048, 1024);
  transpose_k<<<dim3(32, 64), tpb, 0, stream>>>(fg1_w, fg1T, 2048, 1024);

  dim3 gg(8, 32);  // N/128, M/128

  // branch 0 (semantic): q=h_b@wq, k=h_p@wk_syn, v=h_p@wv (transposed out)
  gemm128<float, float><<<gg, 256, 0, stream>>>(h_b, nullptr, wqT, bq, nullptr, nullptr, qb, 1024, 0);
  gemm128<float, float><<<gg, 256, 0, stream>>>(h_p, nullptr, wkSynT, bk_syn, nullptr, nullptr, kb, 1024, 0);
  gemm128<float, float><<<gg, 256, 0, stream>>>(h_p, nullptr, wvT, bv, nullptr, nullptr, vtb, 1024, 3);
  attn_k<<<512, 256, 0, stream>>>(qb, kb, vtb, e0b);

  // branch 1 (syntax): q=h_p@wq, k=h_b@wk_sem, v=h_b@wv
  gemm128<float, float><<<gg, 256, 0, stream>>>(h_p, nullptr, wqT, bq, nullptr, nullptr, qb, 1024, 0);
  gemm128<float, float><<<gg, 256, 0, stream>>>(h_b, nullptr, wkSemT, bk_sem, nullptr, nullptr, kb, 1024, 0);
  gemm128<float, float><<<gg, 256, 0, stream>>>(h_b, nullptr, wvT, bv, nullptr, nullptr, vtb, 1024, 3);
  attn_k<<<512, 256, 0, stream>>>(qb, kb, vtb, e1b);

  // gate fusion (+ residual) -> LN input
  gemm128<float, bf16><<<gg, 256, 0, stream>>>(h_b, e0b, gSemT, g_sem_b, h_b, e0b, ln0, 2048, 1);
  gemm128<float, bf16><<<gg, 256, 0, stream>>>(h_p, e1b, gSynT, g_syn_b, h_p, e1b, ln1, 2048, 1);

  ln_k<<<4096, 256, 0, stream>>>(ln0, ln_sem_g, ln_sem_b, hbp);
  ln_k<<<4096, 256, 0, stream>>>(ln1, ln_syn_g, ln_syn_b, hpp);

  // fg1: relu(cat[hbp,hpp] @ fg1_w + b)
  gemm128<bf16, bf16><<<gg, 256, 0, stream>>>(hbp, hpp, fg1T, fg1_b, nullptr, nullptr, tb, 2048, 2);

  fg2mix_k<<<4096, 256, 0, stream>>>(tb, fg2_w, fg2_b, hbp, hpp, (float*)d_out);
}

// Round 5
// 488.475 us; speedup vs baseline: 1.5978x; 1.5115x over previous
//
#include <hip/hip_runtime.h>

// Inputs/outputs f32; compute bf16 MFMA with f32 accumulation.
// B=4, L=1024, D=1024, H=16, HD=64. M = 4096 tokens per tensor.

typedef __bf16 bf16;
typedef __attribute__((ext_vector_type(4))) __bf16 bf16x4;
typedef __attribute__((ext_vector_type(8))) __bf16 bf16x8;
typedef __attribute__((ext_vector_type(4))) float f32x4;

#define MFMA16(a, b, c) __builtin_amdgcn_mfma_f32_16x16x32_bf16((a), (b), (c), 0, 0, 0)
#define EXP2(x) __builtin_amdgcn_exp2f(x)

// async global->LDS, 16B/lane; LDS dest = wave-uniform base + lane*16
__device__ inline void async16(const bf16* g, bf16* l) {
  __builtin_amdgcn_global_load_lds(
      (const __attribute__((address_space(1))) unsigned int*)g,
      (__attribute__((address_space(3))) unsigned int*)l, 16, 0, 0);
}

// ---------------------------------------------------------------------------
// Weight transpose + f32->bf16: in [R,C] f32 -> out [C,R] bf16
// ---------------------------------------------------------------------------
__global__ __launch_bounds__(256) void transpose_k(const float* __restrict__ in,
                                                   bf16* __restrict__ out,
                                                   int R, int C) {
  __shared__ bf16 tile[32][33];
  int c0 = blockIdx.x * 32, r0 = blockIdx.y * 32;
  int tx = threadIdx.x, ty = threadIdx.y;  // 32 x 8
#pragma unroll
  for (int i = 0; i < 32; i += 8)
    tile[ty + i][tx] = (bf16)in[(size_t)(r0 + ty + i) * C + c0 + tx];
  __syncthreads();
#pragma unroll
  for (int i = 0; i < 32; i += 8)
    out[(size_t)(c0 + ty + i) * R + r0 + tx] = tile[tx][ty + i];
}

// ---------------------------------------------------------------------------
// Shared GEMM helpers: 128x128 tile, 4 waves x 64x64, BK=32.
// ---------------------------------------------------------------------------
__device__ inline void stageA_f32(bf16* As, const float* Asrc, int m0, int tid) {
#pragma unroll
  for (int i = 0; i < 2; i++) {
    int s = tid + i * 256;
    int row = s >> 2, ch = s & 3;
    const float* p = Asrc + (size_t)(m0 + row) * 1024 + ch * 8;
    f32x4 x = *(const f32x4*)p, y = *(const f32x4*)(p + 4);
    bf16x8 r;
#pragma unroll
    for (int j = 0; j < 4; j++) { r[j] = (bf16)x[j]; r[4 + j] = (bf16)y[j]; }
    *(bf16x8*)(As + s * 8) = r;
  }
}
__device__ inline void stageA_bf16(bf16* As, const bf16* Asrc, int m0, int tid) {
#pragma unroll
  for (int i = 0; i < 2; i++) {
    int s = tid + i * 256;
    int row = s >> 2, ch = s & 3;
    async16(Asrc + (size_t)(m0 + row) * 1024 + ch * 8,
            As + ((size_t)(i * 256 + (tid & ~63))) * 8);
  }
}
__device__ inline void stageB(bf16* Bs, const bf16* Wt, int n0, int k0, int ldk,
                              int tid) {
#pragma unroll
  for (int i = 0; i < 2; i++) {
    int s = tid + i * 256;
    int row = s >> 2, ch = s & 3;
    async16(Wt + (size_t)(n0 + row) * ldk + k0 + ch * 8,
            Bs + ((size_t)(i * 256 + (tid & ~63))) * 8);
  }
}

// ---------------------------------------------------------------------------
// Fused projection GEMM: one dispatch computes all 6 QKV projections.
// grid (24, 64): y<32 -> A=h_b (half 0), else A=h_p (half 1). x -> 3 segments
// of 1024 cols: seg0=wq, seg1=wk_(sem|syn), seg2=wv (transposed V output).
// ---------------------------------------------------------------------------
__global__ __launch_bounds__(256) void proj_gemm(
    const float* __restrict__ h_b, const float* __restrict__ h_p,
    const bf16* __restrict__ wqT, const bf16* __restrict__ wkSemT,
    const bf16* __restrict__ wkSynT, const bf16* __restrict__ wvT,
    const float* __restrict__ bq, const float* __restrict__ bk_sem,
    const float* __restrict__ bk_syn, const float* __restrict__ bv,
    bf16* __restrict__ q0, bf16* __restrict__ q1, bf16* __restrict__ k0b,
    bf16* __restrict__ k1b, bf16* __restrict__ v0t, bf16* __restrict__ v1t) {
  __shared__ bf16 As[128 * 32];
  __shared__ bf16 Bs[128 * 32];
  int tid = threadIdx.x;
  int m0g = blockIdx.y * 128;
  int half = m0g >= 4096;
  int m0 = m0g & 4095;
  int n0g = blockIdx.x * 128;
  int seg = n0g >> 10, n0 = n0g & 1023;

  const float* A = half ? h_p : h_b;
  const bf16* Wt = (seg == 0) ? wqT
                   : (seg == 1) ? (half ? wkSynT : wkSemT) : wvT;
  const float* bias = (seg == 0) ? bq
                      : (seg == 1) ? (half ? bk_syn : bk_sem) : bv;

  int w = tid >> 6, lane = tid & 63, quad = lane >> 4, ln = lane & 15;
  int wm = (w >> 1) * 64, wn = (w & 1) * 64;

  const f32x4 z = {0.f, 0.f, 0.f, 0.f};
  f32x4 acc[4][4];
#pragma unroll
  for (int i = 0; i < 4; i++)
#pragma unroll
    for (int j = 0; j < 4; j++) acc[i][j] = z;

  for (int k0 = 0; k0 < 1024; k0 += 32) {
    __syncthreads();
    stageB(Bs, Wt, n0, k0, 1024, tid);
    stageA_f32(As, A + k0, m0, tid);
    __syncthreads();
    bf16x8 af[4], bfv[4];
#pragma unroll
    for (int mt = 0; mt < 4; mt++)
      af[mt] = *(bf16x8*)(As + (wm + mt * 16 + ln) * 32 + quad * 8);
#pragma unroll
    for (int nt = 0; nt < 4; nt++)
      bfv[nt] = *(bf16x8*)(Bs + (wn + nt * 16 + ln) * 32 + quad * 8);
#pragma unroll
    for (int mt = 0; mt < 4; mt++)
#pragma unroll
      for (int nt = 0; nt < 4; nt++)
        acc[mt][nt] = MFMA16(af[mt], bfv[nt], acc[mt][nt]);
  }

  if (seg == 2) {  // V: transposed store  vt[n][token]
    bf16* vt = half ? v0t : v1t;
#pragma unroll
    for (int nt = 0; nt < 4; nt++) {
      int n = n0 + wn + nt * 16 + ln;
      float bvv = bias[n];
#pragma unroll
      for (int mt = 0; mt < 4; mt++) {
        int mb = m0 + wm + mt * 16 + quad * 4;
        bf16x4 pk;
#pragma unroll
        for (int r = 0; r < 4; r++) pk[r] = (bf16)(acc[mt][nt][r] + bvv);
        *(bf16x4*)(vt + (size_t)n * 4096 + mb) = pk;
      }
    }
    return;
  }
  bf16* out = (seg == 0) ? (half ? q1 : q0) : (half ? k0b : k1b);
#pragma unroll
  for (int nt = 0; nt < 4; nt++) {
    int n = n0 + wn + nt * 16 + ln;
    float bvv = bias[n];
#pragma unroll
    for (int mt = 0; mt < 4; mt++) {
      int mb = m0 + wm + mt * 16 + quad * 4;
#pragma unroll
      for (int r = 0; r < 4; r++)
        out[(size_t)(mb + r) * 1024 + n] = (bf16)(acc[mt][nt][r] + bvv);
    }
  }
}

// ---------------------------------------------------------------------------
// Fused gate GEMM (both branches): M=8192 stacked, K=2048, N=1024.
// g = sigmoid([A0|A1] @ W + b); out = g*enh + (1-g)*orig + orig
// ---------------------------------------------------------------------------
__global__ __launch_bounds__(256) void gate_gemm(
    const float* __restrict__ h_b, const float* __restrict__ h_p,
    const bf16* __restrict__ e0, const bf16* __restrict__ e1,
    const bf16* __restrict__ gSemT, const bf16* __restrict__ gSynT,
    const float* __restrict__ g_sem_b, const float* __restrict__ g_syn_b,
    bf16* __restrict__ ln0, bf16* __restrict__ ln1) {
  __shared__ bf16 As[128 * 32];
  __shared__ bf16 Bs[128 * 32];
  int tid = threadIdx.x;
  int m0g = blockIdx.y * 128;
  int half = m0g >= 4096;
  int m0 = m0g & 4095;
  int n0 = blockIdx.x * 128;

  const float* A0 = half ? h_p : h_b;
  const bf16* A1 = half ? e1 : e0;
  const bf16* Wt = half ? gSynT : gSemT;
  const float* bias = half ? g_syn_b : g_sem_b;
  bf16* out = half ? ln1 : ln0;

  int w = tid >> 6, lane = tid & 63, quad = lane >> 4, ln = lane & 15;
  int wm = (w >> 1) * 64, wn = (w & 1) * 64;

  const f32x4 z = {0.f, 0.f, 0.f, 0.f};
  f32x4 acc[4][4];
#pragma unroll
  for (int i = 0; i < 4; i++)
#pragma unroll
    for (int j = 0; j < 4; j++) acc[i][j] = z;

  for (int k0 = 0; k0 < 2048; k0 += 32) {
    __syncthreads();
    stageB(Bs, Wt, n0, k0, 2048, tid);
    if (k0 < 1024)
      stageA_f32(As, A0 + k0, m0, tid);
    else
      stageA_bf16(As, A1 + (k0 - 1024), m0, tid);
    __syncthreads();
    bf16x8 af[4], bfv[4];
#pragma unroll
    for (int mt = 0; mt < 4; mt++)
      af[mt] = *(bf16x8*)(As + (wm + mt * 16 + ln) * 32 + quad * 8);
#pragma unroll
    for (int nt = 0; nt < 4; nt++)
      bfv[nt] = *(bf16x8*)(Bs + (wn + nt * 16 + ln) * 32 + quad * 8);
#pragma unroll
    for (int mt = 0; mt < 4; mt++)
#pragma unroll
      for (int nt = 0; nt < 4; nt++)
        acc[mt][nt] = MFMA16(af[mt], bfv[nt], acc[mt][nt]);
  }

#pragma unroll
  for (int nt = 0; nt < 4; nt++) {
    int n = n0 + wn + nt * 16 + ln;
    float bvv = bias[n];
#pragma unroll
    for (int mt = 0; mt < 4; mt++) {
      int mb = m0 + wm + mt * 16 + quad * 4;
#pragma unroll
      for (int r = 0; r < 4; r++) {
        size_t idx = (size_t)(mb + r) * 1024 + n;
        float v = acc[mt][nt][r] + bvv;
        float e = (float)A1[idx], o = A0[idx];
        float g = 1.f / (1.f + __expf(-v));
        out[idx] = (bf16)(g * e + (1.f - g) * o + o);
      }
    }
  }
}

// ---------------------------------------------------------------------------
// fg1 GEMM: relu(cat[hbp,hpp] @ fg1_w + b). M=4096,K=2048,N=1024.
// ---------------------------------------------------------------------------
__global__ __launch_bounds__(256) void fg1_gemm(
    const bf16* __restrict__ A0, const bf16* __restrict__ A1,
    const bf16* __restrict__ Wt, const float* __restrict__ bias,
    bf16* __restrict__ out) {
  __shared__ bf16 As[128 * 32];
  __shared__ bf16 Bs[128 * 32];
  int tid = threadIdx.x;
  int m0 = blockIdx.y * 128, n0 = blockIdx.x * 128;
  int w = tid >> 6, lane = tid & 63, quad = lane >> 4, ln = lane & 15;
  int wm = (w >> 1) * 64, wn = (w & 1) * 64;

  const f32x4 z = {0.f, 0.f, 0.f, 0.f};
  f32x4 acc[4][4];
#pragma unroll
  for (int i = 0; i < 4; i++)
#pragma unroll
    for (int j = 0; j < 4; j++) acc[i][j] = z;

  for (int k0 = 0; k0 < 2048; k0 += 32) {
    __syncthreads();
    stageB(Bs, Wt, n0, k0, 2048, tid);
    if (k0 < 1024)
      stageA_bf16(As, A0 + k0, m0, tid);
    else
      stageA_bf16(As, A1 + (k0 - 1024), m0, tid);
    __syncthreads();
    bf16x8 af[4], bfv[4];
#pragma unroll
    for (int mt = 0; mt < 4; mt++)
      af[mt] = *(bf16x8*)(As + (wm + mt * 16 + ln) * 32 + quad * 8);
#pragma unroll
    for (int nt = 0; nt < 4; nt++)
      bfv[nt] = *(bf16x8*)(Bs + (wn + nt * 16 + ln) * 32 + quad * 8);
#pragma unroll
    for (int mt = 0; mt < 4; mt++)
#pragma unroll
      for (int nt = 0; nt < 4; nt++)
        acc[mt][nt] = MFMA16(af[mt], bfv[nt], acc[mt][nt]);
  }

#pragma unroll
  for (int nt = 0; nt < 4; nt++) {
    int n = n0 + wn + nt * 16 + ln;
    float bvv = bias[n];
#pragma unroll
    for (int mt = 0; mt < 4; mt++) {
      int mb = m0 + wm + mt * 16 + quad * 4;
#pragma unroll
      for (int r = 0; r < 4; r++)
        out[(size_t)(mb + r) * 1024 + n] =
            (bf16)fmaxf(acc[mt][nt][r] + bvv, 0.f);
    }
  }
}

// ---------------------------------------------------------------------------
// Fused flash attention, both branches in one dispatch. grid 2048.
// Block = (branch, bh, 64 q rows); 4 waves x 16 q rows. kv-tile 64.
// exp2-domain softmax: scores scaled by log2(e)/8 once.
// ---------------------------------------------------------------------------
__global__ __launch_bounds__(256) void attn_k(
    const bf16* __restrict__ q0, const bf16* __restrict__ q1,
    const bf16* __restrict__ k0b, const bf16* __restrict__ k1b,
    const bf16* __restrict__ v0t, const bf16* __restrict__ v1t,
    bf16* __restrict__ e0, bf16* __restrict__ e1) {
  int x = blockIdx.x;
  int branch = (x >> 3) & 1;
  int bh = (x & 7) * 8 + ((x >> 4) & 7);
  int qblk = x >> 7;
  int h = bh & 15, b = bh >> 4;
  const bf16* Q = branch ? q1 : q0;
  const bf16* Kp = branch ? k1b : k0b;
  const bf16* Vg = branch ? v1t : v0t;
  bf16* O = branch ? e1 : e0;
  size_t kbase = ((size_t)b * 1024) * 1024 + h * 64;
  size_t vbase = (size_t)h * 64 * 4096 + b * 1024;

  __shared__ bf16 Kt[2 * 64 * 32];    // [dhalf][k][32]
  __shared__ bf16 Vt[2 * 64 * 32];    // [khalf][d][32]
  __shared__ bf16 Pw[4][2 * 16 * 32]; // per wave: [khalf][q][32]

  int tid = threadIdx.x, w = tid >> 6, lane = tid & 63;
  int quad = lane >> 4, ln = lane & 15;
  int wq0 = qblk * 64 + w * 16;

  bf16x8 qf0 = *(const bf16x8*)(Q + kbase + (size_t)(wq0 + ln) * 1024 + quad * 8);
  bf16x8 qf1 =
      *(const bf16x8*)(Q + kbase + (size_t)(wq0 + ln) * 1024 + 32 + quad * 8);

  const f32x4 z = {0.f, 0.f, 0.f, 0.f};
  f32x4 oacc[4];
#pragma unroll
  for (int i = 0; i < 4; i++) oacc[i] = z;
  float m_run[4], l_run[4];
#pragma unroll
  for (int r = 0; r < 4; r++) { m_run[r] = -1e30f; l_run[r] = 0.f; }
  const float SC = 0.125f * 1.44269504f;  // log2-domain score scale

  for (int kv0 = 0; kv0 < 1024; kv0 += 64) {
    __syncthreads();
#pragma unroll
    for (int i = 0; i < 2; i++) {
      int s = tid + i * 256;  // half=s>>8, row=(s>>2)&63, ch=s&3
      size_t wb = (size_t)(i * 256 + (tid & ~63)) * 8;
      async16(Kp + kbase + (size_t)(kv0 + ((s >> 2) & 63)) * 1024 +
                  (s >> 8) * 32 + (s & 3) * 8,
              Kt + wb);
      async16(Vg + vbase + (size_t)((s >> 2) & 63) * 4096 + kv0 +
                  (s >> 8) * 32 + (s & 3) * 8,
              Vt + wb);
    }
    __syncthreads();

    f32x4 s[4];
#pragma unroll
    for (int nt = 0; nt < 4; nt++) {
      bf16x8 kf0 = *(bf16x8*)(Kt + (nt * 16 + ln) * 32 + quad * 8);
      bf16x8 kf1 = *(bf16x8*)(Kt + 2048 + (nt * 16 + ln) * 32 + quad * 8);
      f32x4 a = z;
      a = MFMA16(qf0, kf0, a);
      a = MFMA16(qf1, kf1, a);
      s[nt] = a * SC;
    }

    float mx[4];
#pragma unroll
    for (int r = 0; r < 4; r++)
      mx[r] = fmaxf(fmaxf(s[0][r], s[1][r]), fmaxf(s[2][r], s[3][r]));
#pragma unroll
    for (int msk = 1; msk < 16; msk <<= 1)
#pragma unroll
      for (int r = 0; r < 4; r++) mx[r] = fmaxf(mx[r], __shfl_xor(mx[r], msk, 64));

    float alpha[4];
#pragma unroll
    for (int r = 0; r < 4; r++) {
      float mn = fmaxf(m_run[r], mx[r]);
      alpha[r] = EXP2(m_run[r] - mn);
      m_run[r] = mn;
    }
    float rs[4] = {0.f, 0.f, 0.f, 0.f};
#pragma unroll
    for (int nt = 0; nt < 4; nt++)
#pragma unroll
      for (int r = 0; r < 4; r++) {
        float p = EXP2(s[nt][r] - m_run[r]);
        s[nt][r] = p;
        rs[r] += p;
      }
#pragma unroll
    for (int msk = 1; msk < 16; msk <<= 1)
#pragma unroll
      for (int r = 0; r < 4; r++) rs[r] += __shfl_xor(rs[r], msk, 64);
#pragma unroll
    for (int r = 0; r < 4; r++) l_run[r] = l_run[r] * alpha[r] + rs[r];
#pragma unroll
    for (int dt = 0; dt < 4; dt++)
#pragma unroll
      for (int r = 0; r < 4; r++) oacc[dt][r] *= alpha[r];

    // P: C-layout -> per-wave LDS [khalf][q][32] (wave-local)
#pragma unroll
    for (int nt = 0; nt < 4; nt++)
#pragma unroll
      for (int r = 0; r < 4; r++)
        Pw[w][(nt >> 1) * 512 + (quad * 4 + r) * 32 + (nt & 1) * 16 + ln] =
            (bf16)s[nt][r];

    bf16x8 pa0 = *(bf16x8*)(Pw[w] + ln * 32 + quad * 8);
    bf16x8 pa1 = *(bf16x8*)(Pw[w] + 512 + ln * 32 + quad * 8);
#pragma unroll
    for (int dt = 0; dt < 4; dt++) {
      bf16x8 vb0 = *(bf16x8*)(Vt + (dt * 16 + ln) * 32 + quad * 8);
      bf16x8 vb1 = *(bf16x8*)(Vt + 2048 + (dt * 16 + ln) * 32 + quad * 8);
      oacc[dt] = MFMA16(pa0, vb0, oacc[dt]);
      oacc[dt] = MFMA16(pa1, vb1, oacc[dt]);
    }
  }

#pragma unroll
  for (int dt = 0; dt < 4; dt++)
#pragma unroll
    for (int r = 0; r < 4; r++) {
      int q = wq0 + quad * 4 + r;
      O[kbase + (size_t)q * 1024 + dt * 16 + ln] =
          (bf16)(oacc[dt][r] / l_run[r]);
    }
}

// ---------------------------------------------------------------------------
// Merged LayerNorm (both branches), D=1024, one block per row. grid 8192.
// ---------------------------------------------------------------------------
__global__ __launch_bounds__(256) void ln_k(
    const bf16* __restrict__ x0, const bf16* __restrict__ x1,
    const float* __restrict__ g0, const float* __restrict__ b0,
    const float* __restrict__ g1, const float* __restrict__ b1,
    bf16* __restrict__ y0, bf16* __restrict__ y1) {
  int rowg = blockIdx.x, tid = threadIdx.x, c = tid * 4;
  int half = rowg >= 4096;
  int row = rowg & 4095;
  const bf16* x = half ? x1 : x0;
  const float* gg = half ? g1 : g0;
  const float* bb = half ? b1 : b0;
  bf16* y = half ? y1 : y0;

  bf16x4 x4 = *(const bf16x4*)(x + (size_t)row * 1024 + c);
  float v[4], s = 0.f, ss = 0.f;
#pragma unroll
  for (int i = 0; i < 4; i++) {
    v[i] = (float)x4[i];
    s += v[i];
    ss += v[i] * v[i];
  }
#pragma unroll
  for (int o = 32; o > 0; o >>= 1) {
    s += __shfl_down(s, o, 64);
    ss += __shfl_down(ss, o, 64);
  }
  __shared__ float red[8];
  int w = tid >> 6;
  if ((tid & 63) == 0) { red[w] = s; red[4 + w] = ss; }
  __syncthreads();
  s = red[0] + red[1] + red[2] + red[3];
  ss = red[4] + red[5] + red[6] + red[7];
  float mu = s * (1.f / 1024.f);
  float var = ss * (1.f / 1024.f) - mu * mu;
  float rstd = rsqrtf(var + 1e-5f);
  f32x4 g4 = *(const f32x4*)(gg + c), b4 = *(const f32x4*)(bb + c);
  bf16x4 o4;
#pragma unroll
  for (int i = 0; i < 4; i++) o4[i] = (bf16)((v[i] - mu) * rstd * g4[i] + b4[i]);
  *(bf16x4*)(y + (size_t)row * 1024 + c) = o4;
}

// ---------------------------------------------------------------------------
// fw = sigmoid(t . w2 + b2); out = fw*hbp + (1-fw)*hpp  (block per row)
// ---------------------------------------------------------------------------
__global__ __launch_bounds__(256) void fg2mix_k(const bf16* __restrict__ t,
                                                const float* __restrict__ w2,
                                                const float* __restrict__ b2,
                                                const bf16* __restrict__ hbp,
                                                const bf16* __restrict__ hpp,
                                                float* __restrict__ out) {
  int row = blockIdx.x, tid = threadIdx.x, c = tid * 4;
  bf16x4 t4 = *(const bf16x4*)(t + (size_t)row * 1024 + c);
  f32x4 w4 = *(const f32x4*)(w2 + c);
  float s = 0.f;
#pragma unroll
  for (int i = 0; i < 4; i++) s += (float)t4[i] * w4[i];
#pragma unroll
  for (int o = 32; o > 0; o >>= 1) s += __shfl_down(s, o, 64);
  __shared__ float red[4];
  if ((tid & 63) == 0) red[tid >> 6] = s;
  __syncthreads();
  s = red[0] + red[1] + red[2] + red[3];
  float fw = 1.f / (1.f + __expf(-(s + b2[0])));
  bf16x4 a4 = *(const bf16x4*)(hbp + (size_t)row * 1024 + c);
  bf16x4 p4 = *(const bf16x4*)(hpp + (size_t)row * 1024 + c);
  f32x4 o4;
#pragma unroll
  for (int i = 0; i < 4; i++)
    o4[i] = fw * (float)a4[i] + (1.f - fw) * (float)p4[i];
  *(f32x4*)(out + (size_t)row * 1024 + c) = o4;
}

// ---------------------------------------------------------------------------
extern "C" void kernel_launch(void* const* d_in, const int* in_sizes, int n_in,
                              void* d_out, int out_size, void* d_ws,
                              size_t ws_size, hipStream_t stream) {
  const float* h_b     = (const float*)d_in[0];
  const float* h_p     = (const float*)d_in[1];
  const float* wq      = (const float*)d_in[2];
  const float* bq      = (const float*)d_in[3];
  const float* wk_sem  = (const float*)d_in[4];
  const float* bk_sem  = (const float*)d_in[5];
  const float* wk_syn  = (const float*)d_in[6];
  const float* bk_syn  = (const float*)d_in[7];
  const float* wv      = (const float*)d_in[8];
  const float* bv      = (const float*)d_in[9];
  const float* g_sem_w = (const float*)d_in[10];
  const float* g_sem_b = (const float*)d_in[11];
  const float* g_syn_w = (const float*)d_in[12];
  const float* g_syn_b = (const float*)d_in[13];
  const float* ln_sem_g = (const float*)d_in[14];
  const float* ln_sem_b = (const float*)d_in[15];
  const float* ln_syn_g = (const float*)d_in[16];
  const float* ln_syn_b = (const float*)d_in[17];
  const float* fg1_w   = (const float*)d_in[18];
  const float* fg1_b   = (const float*)d_in[19];
  const float* fg2_w   = (const float*)d_in[20];
  const float* fg2_b   = (const float*)d_in[21];

  // workspace: 42M bf16 = 84 MB
  bf16* ws = (bf16*)d_ws;
  const size_t M1 = 1024ull * 1024ull;
  bf16* wqT    = ws + 0 * M1;   // [1024][1024]
  bf16* wkSemT = ws + 1 * M1;
  bf16* wkSynT = ws + 2 * M1;
  bf16* wvT    = ws + 3 * M1;
  bf16* gSemT  = ws + 4 * M1;   // [1024][2048]
  bf16* gSynT  = ws + 6 * M1;
  bf16* fg1T   = ws + 8 * M1;
  bf16* q0  = ws + 10 * M1;  // [4096][1024]
  bf16* q1  = ws + 14 * M1;
  bf16* k0b = ws + 18 * M1;
  bf16* k1b = ws + 22 * M1;
  bf16* v0t = ws + 26 * M1;  // [1024][4096]
  bf16* v1t = ws + 30 * M1;
  bf16* e0b = ws + 34 * M1;
  bf16* e1b = ws + 38 * M1;
  // aliases over dead buffers
  bf16* ln0 = q0;   // after attn, q dead
  bf16* ln1 = q1;
  bf16* hbp = k0b;  // after gate gemm, k dead
  bf16* hpp = k1b;
  bf16* tb  = v0t;

  dim3 tpb(32, 8);
  transpose_k<<<dim3(32, 32), tpb, 0, stream>>>(wq, wqT, 1024, 1024);
  transpose_k<<<dim3(32, 32), tpb, 0, stream>>>(wk_sem, wkSemT, 1024, 1024);
  transpose_k<<<dim3(32, 32), tpb, 0, stream>>>(wk_syn, wkSynT, 1024, 1024);
  transpose_k<<<dim3(32, 32), tpb, 0, stream>>>(wv, wvT, 1024, 1024);
  transpose_k<<<dim3(32, 64), tpb, 0, stream>>>(g_sem_w, gSemT, 2048, 1024);
  transpose_k<<<dim3(32, 64), tpb, 0, stream>>>(g_syn_w, gSynT, 2048, 1024);
  transpose_k<<<dim3(32, 64), tpb, 0, stream>>>(fg1_w, fg1T, 2048, 1024);

  // all 6 projections in one dispatch (1536 blocks)
  proj_gemm<<<dim3(24, 64), 256, 0, stream>>>(
      h_b, h_p, wqT, wkSemT, wkSynT, wvT, bq, bk_sem, bk_syn, bv,
      q0, q1, k0b, k1b, v0t, v1t);

  // both attention branches in one dispatch (2048 blocks)
  attn_k<<<2048, 256, 0, stream>>>(q0, q1, k0b, k1b, v0t, v1t, e0b, e1b);

  // both gate fusions in one dispatch (512 blocks)
  gate_gemm<<<dim3(8, 64), 256, 0, stream>>>(
      h_b, h_p, e0b, e1b, gSemT, gSynT, g_sem_b, g_syn_b, ln0, ln1);

  // both layernorms (8192 blocks)
  ln_k<<<8192, 256, 0, stream>>>(ln0, ln1, ln_sem_g, ln_sem_b, ln_syn_g,
                                 ln_syn_b, hbp, hpp);

  // fg1: relu(cat[hbp,hpp] @ fg1_w + b)
  fg1_gemm<<<dim3(8, 32), 256, 0, stream>>>(hbp, hpp, fg1T, fg1_b, tb);

  fg2mix_k<<<4096, 256, 0, stream>>>(tb, fg2_w, fg2_b, hbp, hpp,
                                     (float*)d_out);
}

// Round 6
// 460.982 us; speedup vs baseline: 1.6931x; 1.0596x over previous
//
#include <hip/hip_runtime.h>

// Inputs/outputs f32; compute bf16 MFMA with f32 accumulation.
// B=4, L=1024, D=1024, H=16, HD=64. M = 4096 tokens per tensor.

typedef __bf16 bf16;
typedef __attribute__((ext_vector_type(4))) __bf16 bf16x4;
typedef __attribute__((ext_vector_type(8))) __bf16 bf16x8;
typedef __attribute__((ext_vector_type(4))) float f32x4;

#define MFMA16(a, b, c) __builtin_amdgcn_mfma_f32_16x16x32_bf16((a), (b), (c), 0, 0, 0)
#define EXP2(x) __builtin_amdgcn_exp2f(x)

// async global->LDS, 16B/lane; LDS dest = wave-uniform base + lane*16
__device__ inline void async16(const bf16* g, bf16* l) {
  __builtin_amdgcn_global_load_lds(
      (const __attribute__((address_space(1))) unsigned int*)g,
      (__attribute__((address_space(3))) unsigned int*)l, 16, 0, 0);
}

// ---------------------------------------------------------------------------
// Prep: all 7 weight transposes (f32 [R,C] -> bf16 [C,R]) in ONE dispatch.
// blocks 0..4095: wq/wk_sem/wk_syn/wv (R=1024), 1024 tiles each.
// blocks 4096..10239: g_sem/g_syn/fg1 (R=2048), 2048 tiles each.
// ---------------------------------------------------------------------------
__global__ __launch_bounds__(256) void prep_k(
    const float* __restrict__ wq, const float* __restrict__ wk_sem,
    const float* __restrict__ wk_syn, const float* __restrict__ wv,
    const float* __restrict__ g_sem_w, const float* __restrict__ g_syn_w,
    const float* __restrict__ fg1_w, bf16* __restrict__ wqT,
    bf16* __restrict__ wkSemT, bf16* __restrict__ wkSynT,
    bf16* __restrict__ wvT, bf16* __restrict__ gSemT,
    bf16* __restrict__ gSynT, bf16* __restrict__ fg1T) {
  __shared__ bf16 t[32][33];
  int blk = blockIdx.x, tid = threadIdx.x;
  const float* in;
  bf16* out;
  int R, tile;
  if (blk < 4096) {
    int which = blk >> 10;
    tile = blk & 1023;
    R = 1024;
    in = (which == 0) ? wq : (which == 1) ? wk_sem : (which == 2) ? wk_syn : wv;
    out = (which == 0) ? wqT
          : (which == 1) ? wkSemT : (which == 2) ? wkSynT : wvT;
  } else {
    int b2 = blk - 4096;
    int which = b2 >> 11;
    tile = b2 & 2047;
    R = 2048;
    in = (which == 0) ? g_sem_w : (which == 1) ? g_syn_w : fg1_w;
    out = (which == 0) ? gSemT : (which == 1) ? gSynT : fg1T;
  }
  const int C = 1024;
  int c0 = (tile & 31) * 32, r0 = (tile >> 5) * 32;
  int tx = tid & 31, ty = tid >> 5;  // 32 x 8
#pragma unroll
  for (int i = 0; i < 32; i += 8)
    t[ty + i][tx] = (bf16)in[(size_t)(r0 + ty + i) * C + c0 + tx];
  __syncthreads();
#pragma unroll
  for (int i = 0; i < 32; i += 8)
    out[(size_t)(c0 + ty + i) * R + r0 + tx] = t[tx][ty + i];
}

// ---------------------------------------------------------------------------
// Shared GEMM helpers: 128x128 tile, 4 waves x 64x64, BK=32.
// ---------------------------------------------------------------------------
__device__ inline void stageA_f32(bf16* As, const float* Asrc, int m0, int tid) {
#pragma unroll
  for (int i = 0; i < 2; i++) {
    int s = tid + i * 256;
    int row = s >> 2, ch = s & 3;
    const float* p = Asrc + (size_t)(m0 + row) * 1024 + ch * 8;
    f32x4 x = *(const f32x4*)p, y = *(const f32x4*)(p + 4);
    bf16x8 r;
#pragma unroll
    for (int j = 0; j < 4; j++) { r[j] = (bf16)x[j]; r[4 + j] = (bf16)y[j]; }
    *(bf16x8*)(As + s * 8) = r;
  }
}
__device__ inline void stageA_bf16(bf16* As, const bf16* Asrc, int m0, int tid) {
#pragma unroll
  for (int i = 0; i < 2; i++) {
    int s = tid + i * 256;
    int row = s >> 2, ch = s & 3;
    async16(Asrc + (size_t)(m0 + row) * 1024 + ch * 8,
            As + ((size_t)(i * 256 + (tid & ~63))) * 8);
  }
}
__device__ inline void stageB(bf16* Bs, const bf16* Wt, int n0, int k0, int ldk,
                              int tid) {
#pragma unroll
  for (int i = 0; i < 2; i++) {
    int s = tid + i * 256;
    int row = s >> 2, ch = s & 3;
    async16(Wt + (size_t)(n0 + row) * ldk + k0 + ch * 8,
            Bs + ((size_t)(i * 256 + (tid & ~63))) * 8);
  }
}

// ---------------------------------------------------------------------------
// Fused projection GEMM: one dispatch computes all 6 QKV projections.
// Q outputs pre-scaled by log2(e)/8 (folded attention score scale).
// ---------------------------------------------------------------------------
__global__ __launch_bounds__(256) void proj_gemm(
    const float* __restrict__ h_b, const float* __restrict__ h_p,
    const bf16* __restrict__ wqT, const bf16* __restrict__ wkSemT,
    const bf16* __restrict__ wkSynT, const bf16* __restrict__ wvT,
    const float* __restrict__ bq, const float* __restrict__ bk_sem,
    const float* __restrict__ bk_syn, const float* __restrict__ bv,
    bf16* __restrict__ q0, bf16* __restrict__ q1, bf16* __restrict__ k0b,
    bf16* __restrict__ k1b, bf16* __restrict__ v0t, bf16* __restrict__ v1t) {
  __shared__ bf16 As[128 * 32];
  __shared__ bf16 Bs[128 * 32];
  int tid = threadIdx.x;
  int m0g = blockIdx.y * 128;
  int half = m0g >= 4096;
  int m0 = m0g & 4095;
  int n0g = blockIdx.x * 128;
  int seg = n0g >> 10, n0 = n0g & 1023;

  const float* A = half ? h_p : h_b;
  const bf16* Wt = (seg == 0) ? wqT
                   : (seg == 1) ? (half ? wkSynT : wkSemT) : wvT;
  const float* bias = (seg == 0) ? bq
                      : (seg == 1) ? (half ? bk_syn : bk_sem) : bv;

  int w = tid >> 6, lane = tid & 63, quad = lane >> 4, ln = lane & 15;
  int wm = (w >> 1) * 64, wn = (w & 1) * 64;

  const f32x4 z = {0.f, 0.f, 0.f, 0.f};
  f32x4 acc[4][4];
#pragma unroll
  for (int i = 0; i < 4; i++)
#pragma unroll
    for (int j = 0; j < 4; j++) acc[i][j] = z;

  for (int k0 = 0; k0 < 1024; k0 += 32) {
    __syncthreads();
    stageB(Bs, Wt, n0, k0, 1024, tid);
    stageA_f32(As, A + k0, m0, tid);
    __syncthreads();
    bf16x8 af[4], bfv[4];
#pragma unroll
    for (int mt = 0; mt < 4; mt++)
      af[mt] = *(bf16x8*)(As + (wm + mt * 16 + ln) * 32 + quad * 8);
#pragma unroll
    for (int nt = 0; nt < 4; nt++)
      bfv[nt] = *(bf16x8*)(Bs + (wn + nt * 16 + ln) * 32 + quad * 8);
#pragma unroll
    for (int mt = 0; mt < 4; mt++)
#pragma unroll
      for (int nt = 0; nt < 4; nt++)
        acc[mt][nt] = MFMA16(af[mt], bfv[nt], acc[mt][nt]);
  }

  if (seg == 2) {  // V: transposed store  vt[n][token]
    bf16* vt = half ? v0t : v1t;
#pragma unroll
    for (int nt = 0; nt < 4; nt++) {
      int n = n0 + wn + nt * 16 + ln;
      float bvv = bias[n];
#pragma unroll
      for (int mt = 0; mt < 4; mt++) {
        int mb = m0 + wm + mt * 16 + quad * 4;
        bf16x4 pk;
#pragma unroll
        for (int r = 0; r < 4; r++) pk[r] = (bf16)(acc[mt][nt][r] + bvv);
        *(bf16x4*)(vt + (size_t)n * 4096 + mb) = pk;
      }
    }
    return;
  }
  const float scale = (seg == 0) ? 0.1803368801f : 1.f;  // log2(e)/8 for Q
  bf16* out = (seg == 0) ? (half ? q1 : q0) : (half ? k0b : k1b);
#pragma unroll
  for (int nt = 0; nt < 4; nt++) {
    int n = n0 + wn + nt * 16 + ln;
    float bvv = bias[n];
#pragma unroll
    for (int mt = 0; mt < 4; mt++) {
      int mb = m0 + wm + mt * 16 + quad * 4;
#pragma unroll
      for (int r = 0; r < 4; r++)
        out[(size_t)(mb + r) * 1024 + n] =
            (bf16)((acc[mt][nt][r] + bvv) * scale);
    }
  }
}

// ---------------------------------------------------------------------------
// Fused gate GEMM (both branches): M=8192 stacked, K=2048, N=1024.
// g = sigmoid([A0|A1] @ W + b); out = g*enh + (1-g)*orig + orig
// ---------------------------------------------------------------------------
__global__ __launch_bounds__(256) void gate_gemm(
    const float* __restrict__ h_b, const float* __restrict__ h_p,
    const bf16* __restrict__ e0, const bf16* __restrict__ e1,
    const bf16* __restrict__ gSemT, const bf16* __restrict__ gSynT,
    const float* __restrict__ g_sem_b, const float* __restrict__ g_syn_b,
    bf16* __restrict__ ln0, bf16* __restrict__ ln1) {
  __shared__ bf16 As[128 * 32];
  __shared__ bf16 Bs[128 * 32];
  int tid = threadIdx.x;
  int m0g = blockIdx.y * 128;
  int half = m0g >= 4096;
  int m0 = m0g & 4095;
  int n0 = blockIdx.x * 128;

  const float* A0 = half ? h_p : h_b;
  const bf16* A1 = half ? e1 : e0;
  const bf16* Wt = half ? gSynT : gSemT;
  const float* bias = half ? g_syn_b : g_sem_b;
  bf16* out = half ? ln1 : ln0;

  int w = tid >> 6, lane = tid & 63, quad = lane >> 4, ln = lane & 15;
  int wm = (w >> 1) * 64, wn = (w & 1) * 64;

  const f32x4 z = {0.f, 0.f, 0.f, 0.f};
  f32x4 acc[4][4];
#pragma unroll
  for (int i = 0; i < 4; i++)
#pragma unroll
    for (int j = 0; j < 4; j++) acc[i][j] = z;

  for (int k0 = 0; k0 < 2048; k0 += 32) {
    __syncthreads();
    stageB(Bs, Wt, n0, k0, 2048, tid);
    if (k0 < 1024)
      stageA_f32(As, A0 + k0, m0, tid);
    else
      stageA_bf16(As, A1 + (k0 - 1024), m0, tid);
    __syncthreads();
    bf16x8 af[4], bfv[4];
#pragma unroll
    for (int mt = 0; mt < 4; mt++)
      af[mt] = *(bf16x8*)(As + (wm + mt * 16 + ln) * 32 + quad * 8);
#pragma unroll
    for (int nt = 0; nt < 4; nt++)
      bfv[nt] = *(bf16x8*)(Bs + (wn + nt * 16 + ln) * 32 + quad * 8);
#pragma unroll
    for (int mt = 0; mt < 4; mt++)
#pragma unroll
      for (int nt = 0; nt < 4; nt++)
        acc[mt][nt] = MFMA16(af[mt], bfv[nt], acc[mt][nt]);
  }

#pragma unroll
  for (int nt = 0; nt < 4; nt++) {
    int n = n0 + wn + nt * 16 + ln;
    float bvv = bias[n];
#pragma unroll
    for (int mt = 0; mt < 4; mt++) {
      int mb = m0 + wm + mt * 16 + quad * 4;
#pragma unroll
      for (int r = 0; r < 4; r++) {
        size_t idx = (size_t)(mb + r) * 1024 + n;
        float v = acc[mt][nt][r] + bvv;
        float e = (float)A1[idx], o = A0[idx];
        float g = 1.f / (1.f + __expf(-v));
        out[idx] = (bf16)(g * e + (1.f - g) * o + o);
      }
    }
  }
}

// ---------------------------------------------------------------------------
// fg1 GEMM: relu(cat[hbp,hpp] @ fg1_w + b). M=4096,K=2048,N=1024.
// ---------------------------------------------------------------------------
__global__ __launch_bounds__(256) void fg1_gemm(
    const bf16* __restrict__ A0, const bf16* __restrict__ A1,
    const bf16* __restrict__ Wt, const float* __restrict__ bias,
    bf16* __restrict__ out) {
  __shared__ bf16 As[128 * 32];
  __shared__ bf16 Bs[128 * 32];
  int tid = threadIdx.x;
  int m0 = blockIdx.y * 128, n0 = blockIdx.x * 128;
  int w = tid >> 6, lane = tid & 63, quad = lane >> 4, ln = lane & 15;
  int wm = (w >> 1) * 64, wn = (w & 1) * 64;

  const f32x4 z = {0.f, 0.f, 0.f, 0.f};
  f32x4 acc[4][4];
#pragma unroll
  for (int i = 0; i < 4; i++)
#pragma unroll
    for (int j = 0; j < 4; j++) acc[i][j] = z;

  for (int k0 = 0; k0 < 2048; k0 += 32) {
    __syncthreads();
    stageB(Bs, Wt, n0, k0, 2048, tid);
    if (k0 < 1024)
      stageA_bf16(As, A0 + k0, m0, tid);
    else
      stageA_bf16(As, A1 + (k0 - 1024), m0, tid);
    __syncthreads();
    bf16x8 af[4], bfv[4];
#pragma unroll
    for (int mt = 0; mt < 4; mt++)
      af[mt] = *(bf16x8*)(As + (wm + mt * 16 + ln) * 32 + quad * 8);
#pragma unroll
    for (int nt = 0; nt < 4; nt++)
      bfv[nt] = *(bf16x8*)(Bs + (wn + nt * 16 + ln) * 32 + quad * 8);
#pragma unroll
    for (int mt = 0; mt < 4; mt++)
#pragma unroll
      for (int nt = 0; nt < 4; nt++)
        acc[mt][nt] = MFMA16(af[mt], bfv[nt], acc[mt][nt]);
  }

#pragma unroll
  for (int nt = 0; nt < 4; nt++) {
    int n = n0 + wn + nt * 16 + ln;
    float bvv = bias[n];
#pragma unroll
    for (int mt = 0; mt < 4; mt++) {
      int mb = m0 + wm + mt * 16 + quad * 4;
#pragma unroll
      for (int r = 0; r < 4; r++)
        out[(size_t)(mb + r) * 1024 + n] =
            (bf16)fmaxf(acc[mt][nt][r] + bvv, 0.f);
    }
  }
}

// ---------------------------------------------------------------------------
// Fused flash attention, both branches, S^T orientation.
// QK^T computed as K·Q^T => C-layout col = q = lane&15: softmax reductions
// are in-lane + 2 cross-quad shuffles; m/l/alpha are per-lane scalars.
// P packed to LDS as b64 writes; PV reads P as A-operand (same frag layout),
// keeping the coalesced O epilogue. Q pre-scaled by log2(e)/8 in proj.
// ---------------------------------------------------------------------------
__global__ __launch_bounds__(256) void attn_k(
    const bf16* __restrict__ q0, const bf16* __restrict__ q1,
    const bf16* __restrict__ k0b, const bf16* __restrict__ k1b,
    const bf16* __restrict__ v0t, const bf16* __restrict__ v1t,
    bf16* __restrict__ e0, bf16* __restrict__ e1) {
  int x = blockIdx.x;
  int branch = (x >> 3) & 1;
  int bh = (x & 7) * 8 + ((x >> 4) & 7);
  int qblk = x >> 7;
  int h = bh & 15, b = bh >> 4;
  const bf16* Q = branch ? q1 : q0;
  const bf16* Kp = branch ? k1b : k0b;
  const bf16* Vg = branch ? v1t : v0t;
  bf16* O = branch ? e1 : e0;
  size_t kbase = ((size_t)b * 1024) * 1024 + h * 64;
  size_t vbase = (size_t)h * 64 * 4096 + b * 1024;

  __shared__ bf16 Kt[2 * 64 * 32];    // [dhalf][k][32]
  __shared__ bf16 Vt[2 * 64 * 32];    // [khalf][d][32]
  __shared__ bf16 Pw[4][2 * 16 * 32]; // per wave: [khalf][q][32]

  int tid = threadIdx.x, w = tid >> 6, lane = tid & 63;
  int quad = lane >> 4, ln = lane & 15;
  int wq0 = qblk * 64 + w * 16;

  // Q as B-operand: B[n=q=ln][kd=quad*8+j]
  bf16x8 qf0 = *(const bf16x8*)(Q + kbase + (size_t)(wq0 + ln) * 1024 + quad * 8);
  bf16x8 qf1 =
      *(const bf16x8*)(Q + kbase + (size_t)(wq0 + ln) * 1024 + 32 + quad * 8);

  const f32x4 z = {0.f, 0.f, 0.f, 0.f};
  f32x4 oacc[4];
#pragma unroll
  for (int i = 0; i < 4; i++) oacc[i] = z;
  float m_run = -1e30f, l_run = 0.f;

  for (int kv0 = 0; kv0 < 1024; kv0 += 64) {
    __syncthreads();
#pragma unroll
    for (int i = 0; i < 2; i++) {
      int s = tid + i * 256;  // half=s>>8, row=(s>>2)&63, ch=s&3
      size_t wb = (size_t)(i * 256 + (tid & ~63)) * 8;
      async16(Kp + kbase + (size_t)(kv0 + ((s >> 2) & 63)) * 1024 +
                  (s >> 8) * 32 + (s & 3) * 8,
              Kt + wb);
      async16(Vg + vbase + (size_t)((s >> 2) & 63) * 4096 + kv0 +
                  (s >> 8) * 32 + (s & 3) * 8,
              Vt + wb);
    }
    __syncthreads();

    // S^T tiles: A = K (m = k-token), B = Q (n = q).
    // Lane holds s[nt][r] = S[k=nt*16+quad*4+r][q=ln] (log2-domain).
    f32x4 s[4];
#pragma unroll
    for (int nt = 0; nt < 4; nt++) {
      bf16x8 kf0 = *(bf16x8*)(Kt + (nt * 16 + ln) * 32 + quad * 8);
      bf16x8 kf1 = *(bf16x8*)(Kt + 2048 + (nt * 16 + ln) * 32 + quad * 8);
      f32x4 a = z;
      a = MFMA16(kf0, qf0, a);
      a = MFMA16(kf1, qf1, a);
      s[nt] = a;
    }

    // per-lane row (q=ln) max over 16 in-lane values + 2 cross-quad shuffles
    float mx = s[0][0];
#pragma unroll
    for (int nt = 0; nt < 4; nt++)
#pragma unroll
      for (int r = 0; r < 4; r++) mx = fmaxf(mx, s[nt][r]);
    mx = fmaxf(mx, __shfl_xor(mx, 16, 64));
    mx = fmaxf(mx, __shfl_xor(mx, 32, 64));

    float mn = fmaxf(m_run, mx);
    float alpha = EXP2(m_run - mn);
    m_run = mn;

    float rs = 0.f;
#pragma unroll
    for (int nt = 0; nt < 4; nt++)
#pragma unroll
      for (int r = 0; r < 4; r++) {
        float p = EXP2(s[nt][r] - mn);
        s[nt][r] = p;
        rs += p;
      }
    rs += __shfl_xor(rs, 16, 64);
    rs += __shfl_xor(rs, 32, 64);
    l_run = l_run * alpha + rs;

    // route alpha (indexed by q=ln) to oacc C-layout rows (q=quad*4+r)
    float a_r[4];
#pragma unroll
    for (int r = 0; r < 4; r++) a_r[r] = __shfl(alpha, quad * 4 + r, 16);
#pragma unroll
    for (int dt = 0; dt < 4; dt++)
#pragma unroll
      for (int r = 0; r < 4; r++) oacc[dt][r] *= a_r[r];

    // P store: lane owns P[q=ln][k=nt*16+quad*4+r] -> r-packed b64 writes
#pragma unroll
    for (int nt = 0; nt < 4; nt++) {
      bf16x4 pk;
#pragma unroll
      for (int r = 0; r < 4; r++) pk[r] = (bf16)s[nt][r];
      *(bf16x4*)(Pw[w] + (nt >> 1) * 512 + ln * 32 + (nt & 1) * 16 + quad * 4) =
          pk;
    }

    // PV: A = P[m=q][k] (same frag layout as B), B = V[n=d][k]
    bf16x8 pa0 = *(bf16x8*)(Pw[w] + ln * 32 + quad * 8);
    bf16x8 pa1 = *(bf16x8*)(Pw[w] + 512 + ln * 32 + quad * 8);
#pragma unroll
    for (int dt = 0; dt < 4; dt++) {
      bf16x8 vb0 = *(bf16x8*)(Vt + (dt * 16 + ln) * 32 + quad * 8);
      bf16x8 vb1 = *(bf16x8*)(Vt + 2048 + (dt * 16 + ln) * 32 + quad * 8);
      oacc[dt] = MFMA16(pa0, vb0, oacc[dt]);
      oacc[dt] = MFMA16(pa1, vb1, oacc[dt]);
    }
  }

  float l_r[4];
#pragma unroll
  for (int r = 0; r < 4; r++)
    l_r[r] = 1.f / __shfl(l_run, quad * 4 + r, 16);
#pragma unroll
  for (int dt = 0; dt < 4; dt++)
#pragma unroll
    for (int r = 0; r < 4; r++) {
      int q = wq0 + quad * 4 + r;
      O[kbase + (size_t)q * 1024 + dt * 16 + ln] =
          (bf16)(oacc[dt][r] * l_r[r]);
    }
}

// ---------------------------------------------------------------------------
// Merged LayerNorm (both branches), D=1024, one block per row. grid 8192.
// ---------------------------------------------------------------------------
__global__ __launch_bounds__(256) void ln_k(
    const bf16* __restrict__ x0, const bf16* __restrict__ x1,
    const float* __restrict__ g0, const float* __restrict__ b0,
    const float* __restrict__ g1, const float* __restrict__ b1,
    bf16* __restrict__ y0, bf16* __restrict__ y1) {
  int rowg = blockIdx.x, tid = threadIdx.x, c = tid * 4;
  int half = rowg >= 4096;
  int row = rowg & 4095;
  const bf16* x = half ? x1 : x0;
  const float* gg = half ? g1 : g0;
  const float* bb = half ? b1 : b0;
  bf16* y = half ? y1 : y0;

  bf16x4 x4 = *(const bf16x4*)(x + (size_t)row * 1024 + c);
  float v[4], s = 0.f, ss = 0.f;
#pragma unroll
  for (int i = 0; i < 4; i++) {
    v[i] = (float)x4[i];
    s += v[i];
    ss += v[i] * v[i];
  }
#pragma unroll
  for (int o = 32; o > 0; o >>= 1) {
    s += __shfl_down(s, o, 64);
    ss += __shfl_down(ss, o, 64);
  }
  __shared__ float red[8];
  int w = tid >> 6;
  if ((tid & 63) == 0) { red[w] = s; red[4 + w] = ss; }
  __syncthreads();
  s = red[0] + red[1] + red[2] + red[3];
  ss = red[4] + red[5] + red[6] + red[7];
  float mu = s * (1.f / 1024.f);
  float var = ss * (1.f / 1024.f) - mu * mu;
  float rstd = rsqrtf(var + 1e-5f);
  f32x4 g4 = *(const f32x4*)(gg + c), b4 = *(const f32x4*)(bb + c);
  bf16x4 o4;
#pragma unroll
  for (int i = 0; i < 4; i++) o4[i] = (bf16)((v[i] - mu) * rstd * g4[i] + b4[i]);
  *(bf16x4*)(y + (size_t)row * 1024 + c) = o4;
}

// ---------------------------------------------------------------------------
// fw = sigmoid(t . w2 + b2); out = fw*hbp + (1-fw)*hpp  (block per row)
// ---------------------------------------------------------------------------
__global__ __launch_bounds__(256) void fg2mix_k(const bf16* __restrict__ t,
                                                const float* __restrict__ w2,
                                                const float* __restrict__ b2,
                                                const bf16* __restrict__ hbp,
                                                const bf16* __restrict__ hpp,
                                                float* __restrict__ out) {
  int row = blockIdx.x, tid = threadIdx.x, c = tid * 4;
  bf16x4 t4 = *(const bf16x4*)(t + (size_t)row * 1024 + c);
  f32x4 w4 = *(const f32x4*)(w2 + c);
  float s = 0.f;
#pragma unroll
  for (int i = 0; i < 4; i++) s += (float)t4[i] * w4[i];
#pragma unroll
  for (int o = 32; o > 0; o >>= 1) s += __shfl_down(s, o, 64);
  __shared__ float red[4];
  if ((tid & 63) == 0) red[tid >> 6] = s;
  __syncthreads();
  s = red[0] + red[1] + red[2] + red[3];
  float fw = 1.f / (1.f + __expf(-(s + b2[0])));
  bf16x4 a4 = *(const bf16x4*)(hbp + (size_t)row * 1024 + c);
  bf16x4 p4 = *(const bf16x4*)(hpp + (size_t)row * 1024 + c);
  f32x4 o4;
#pragma unroll
  for (int i = 0; i < 4; i++)
    o4[i] = fw * (float)a4[i] + (1.f - fw) * (float)p4[i];
  *(f32x4*)(out + (size_t)row * 1024 + c) = o4;
}

// ---------------------------------------------------------------------------
extern "C" void kernel_launch(void* const* d_in, const int* in_sizes, int n_in,
                              void* d_out, int out_size, void* d_ws,
                              size_t ws_size, hipStream_t stream) {
  const float* h_b     = (const float*)d_in[0];
  const float* h_p     = (const float*)d_in[1];
  const float* wq      = (const float*)d_in[2];
  const float* bq      = (const float*)d_in[3];
  const float* wk_sem  = (const float*)d_in[4];
  const float* bk_sem  = (const float*)d_in[5];
  const float* wk_syn  = (const float*)d_in[6];
  const float* bk_syn  = (const float*)d_in[7];
  const float* wv      = (const float*)d_in[8];
  const float* bv      = (const float*)d_in[9];
  const float* g_sem_w = (const float*)d_in[10];
  const float* g_sem_b = (const float*)d_in[11];
  const float* g_syn_w = (const float*)d_in[12];
  const float* g_syn_b = (const float*)d_in[13];
  const float* ln_sem_g = (const float*)d_in[14];
  const float* ln_sem_b = (const float*)d_in[15];
  const float* ln_syn_g = (const float*)d_in[16];
  const float* ln_syn_b = (const float*)d_in[17];
  const float* fg1_w   = (const float*)d_in[18];
  const float* fg1_b   = (const float*)d_in[19];
  const float* fg2_w   = (const float*)d_in[20];
  const float* fg2_b   = (const float*)d_in[21];

  // workspace: 42M bf16 = 84 MB
  bf16* ws = (bf16*)d_ws;
  const size_t M1 = 1024ull * 1024ull;
  bf16* wqT    = ws + 0 * M1;   // [1024][1024]
  bf16* wkSemT = ws + 1 * M1;
  bf16* wkSynT = ws + 2 * M1;
  bf16* wvT    = ws + 3 * M1;
  bf16* gSemT  = ws + 4 * M1;   // [1024][2048]
  bf16* gSynT  = ws + 6 * M1;
  bf16* fg1T   = ws + 8 * M1;
  bf16* q0  = ws + 10 * M1;  // [4096][1024]
  bf16* q1  = ws + 14 * M1;
  bf16* k0b = ws + 18 * M1;
  bf16* k1b = ws + 22 * M1;
  bf16* v0t = ws + 26 * M1;  // [1024][4096]
  bf16* v1t = ws + 30 * M1;
  bf16* e0b = ws + 34 * M1;
  bf16* e1b = ws + 38 * M1;
  // aliases over dead buffers
  bf16* ln0 = q0;   // after attn, q dead
  bf16* ln1 = q1;
  bf16* hbp = k0b;  // after gate gemm, k dead
  bf16* hpp = k1b;
  bf16* tb  = v0t;

  // all 7 weight transposes in one dispatch
  prep_k<<<10240, 256, 0, stream>>>(wq, wk_sem, wk_syn, wv, g_sem_w, g_syn_w,
                                    fg1_w, wqT, wkSemT, wkSynT, wvT, gSemT,
                                    gSynT, fg1T);

  // all 6 projections in one dispatch (1536 blocks)
  proj_gemm<<<dim3(24, 64), 256, 0, stream>>>(
      h_b, h_p, wqT, wkSemT, wkSynT, wvT, bq, bk_sem, bk_syn, bv,
      q0, q1, k0b, k1b, v0t, v1t);

  // both attention branches in one dispatch (2048 blocks)
  attn_k<<<2048, 256, 0, stream>>>(q0, q1, k0b, k1b, v0t, v1t, e0b, e1b);

  // both gate fusions in one dispatch (512 blocks)
  gate_gemm<<<dim3(8, 64), 256, 0, stream>>>(
      h_b, h_p, e0b, e1b, gSemT, gSynT, g_sem_b, g_syn_b, ln0, ln1);

  // both layernorms (8192 blocks)
  ln_k<<<8192, 256, 0, stream>>>(ln0, ln1, ln_sem_g, ln_sem_b, ln_syn_g,
                                 ln_syn_b, hbp, hpp);

  // fg1: relu(cat[hbp,hpp] @ fg1_w + b)
  fg1_gemm<<<dim3(8, 32), 256, 0, stream>>>(hbp, hpp, fg1T, fg1_b, tb);

  fg2mix_k<<<4096, 256, 0, stream>>>(tb, fg2_w, fg2_b, hbp, hpp,
                                     (float*)d_out);
}

// Round 7
// 418.260 us; speedup vs baseline: 1.8660x; 1.1021x over previous
//
#include <hip/hip_runtime.h>

// Inputs/outputs f32; compute bf16 MFMA with f32 accumulation.
// B=4, L=1024, D=1024, H=16, HD=64. M = 4096 tokens per tensor.
// h_b/h_p are pre-converted to bf16 into d_out's storage (written last).

typedef __bf16 bf16;
typedef __attribute__((ext_vector_type(4))) __bf16 bf16x4;
typedef __attribute__((ext_vector_type(8))) __bf16 bf16x8;
typedef __attribute__((ext_vector_type(4))) float f32x4;

#define MFMA16(a, b, c) __builtin_amdgcn_mfma_f32_16x16x32_bf16((a), (b), (c), 0, 0, 0)
#define EXP2(x) __builtin_amdgcn_exp2f(x)

// async global->LDS, 16B/lane; LDS dest = wave-uniform base + lane*16
__device__ inline void async16(const bf16* g, bf16* l) {
  __builtin_amdgcn_global_load_lds(
      (const __attribute__((address_space(1))) unsigned int*)g,
      (__attribute__((address_space(3))) unsigned int*)l, 16, 0, 0);
}

// ---------------------------------------------------------------------------
// Prep: 7 weight transposes (f32 [R,C] -> bf16 [C,R]) + h_b/h_p f32->bf16,
// all in ONE dispatch.
// blocks 0..4095: wq/wk_sem/wk_syn/wv (R=1024). 4096..10239: g/g/fg1 (R=2048).
// blocks 10240..14335: h_b, h_p elementwise convert (2048 blocks each).
// ---------------------------------------------------------------------------
__global__ __launch_bounds__(256) void prep_k(
    const float* __restrict__ wq, const float* __restrict__ wk_sem,
    const float* __restrict__ wk_syn, const float* __restrict__ wv,
    const float* __restrict__ g_sem_w, const float* __restrict__ g_syn_w,
    const float* __restrict__ fg1_w, const float* __restrict__ h_b,
    const float* __restrict__ h_p, bf16* __restrict__ wqT,
    bf16* __restrict__ wkSemT, bf16* __restrict__ wkSynT,
    bf16* __restrict__ wvT, bf16* __restrict__ gSemT,
    bf16* __restrict__ gSynT, bf16* __restrict__ fg1T,
    bf16* __restrict__ hbb, bf16* __restrict__ hpb) {
  int blk = blockIdx.x, tid = threadIdx.x;
  if (blk >= 10240) {  // h_b/h_p conversion
    int idx = blk - 10240;
    const float* in = (idx < 2048) ? h_b : h_p;
    bf16* out = (idx < 2048) ? hbb : hpb;
    size_t base = (size_t)(idx & 2047) * 2048 + tid * 8;
    f32x4 x = *(const f32x4*)(in + base), y = *(const f32x4*)(in + base + 4);
    bf16x8 r;
#pragma unroll
    for (int j = 0; j < 4; j++) { r[j] = (bf16)x[j]; r[4 + j] = (bf16)y[j]; }
    *(bf16x8*)(out + base) = r;
    return;
  }
  __shared__ bf16 t[32][33];
  const float* in;
  bf16* out;
  int R, tile;
  if (blk < 4096) {
    int which = blk >> 10;
    tile = blk & 1023;
    R = 1024;
    in = (which == 0) ? wq : (which == 1) ? wk_sem : (which == 2) ? wk_syn : wv;
    out = (which == 0) ? wqT
          : (which == 1) ? wkSemT : (which == 2) ? wkSynT : wvT;
  } else {
    int b2 = blk - 4096;
    int which = b2 >> 11;
    tile = b2 & 2047;
    R = 2048;
    in = (which == 0) ? g_sem_w : (which == 1) ? g_syn_w : fg1_w;
    out = (which == 0) ? gSemT : (which == 1) ? gSynT : fg1T;
  }
  const int C = 1024;
  int c0 = (tile & 31) * 32, r0 = (tile >> 5) * 32;
  int tx = tid & 31, ty = tid >> 5;  // 32 x 8
#pragma unroll
  for (int i = 0; i < 32; i += 8)
    t[ty + i][tx] = (bf16)in[(size_t)(r0 + ty + i) * C + c0 + tx];
  __syncthreads();
#pragma unroll
  for (int i = 0; i < 32; i += 8)
    out[(size_t)(c0 + ty + i) * R + r0 + tx] = t[tx][ty + i];
}

// ---------------------------------------------------------------------------
// Shared GEMM helpers. All staging via global_load_lds width-16.
// ---------------------------------------------------------------------------
__device__ inline void stage128(bf16* Ls, const bf16* src, int r0, int k0,
                                int ldk, int tid) {
#pragma unroll
  for (int i = 0; i < 2; i++) {
    int s = tid + i * 256;
    int row = s >> 2, ch = s & 3;
    async16(src + (size_t)(r0 + row) * ldk + k0 + ch * 8,
            Ls + ((size_t)(i * 256 + (tid & ~63))) * 8);
  }
}
__device__ inline void stage64(bf16* Ls, const bf16* src, int r0, int k0,
                               int ldk, int tid) {
  int row = tid >> 2, ch = tid & 3;
  async16(src + (size_t)(r0 + row) * ldk + k0 + ch * 8,
          Ls + ((size_t)(tid & ~63)) * 8);
}

// ---------------------------------------------------------------------------
// Fused projection GEMM: one dispatch, all 6 QKV projections.
// Q outputs pre-scaled by log2(e)/8 (folded attention score scale).
// ---------------------------------------------------------------------------
__global__ __launch_bounds__(256) void proj_gemm(
    const bf16* __restrict__ hbb, const bf16* __restrict__ hpb,
    const bf16* __restrict__ wqT, const bf16* __restrict__ wkSemT,
    const bf16* __restrict__ wkSynT, const bf16* __restrict__ wvT,
    const float* __restrict__ bq, const float* __restrict__ bk_sem,
    const float* __restrict__ bk_syn, const float* __restrict__ bv,
    bf16* __restrict__ q0, bf16* __restrict__ q1, bf16* __restrict__ k0b,
    bf16* __restrict__ k1b, bf16* __restrict__ v0t, bf16* __restrict__ v1t) {
  __shared__ bf16 As[128 * 32];
  __shared__ bf16 Bs[128 * 32];
  int tid = threadIdx.x;
  int m0g = blockIdx.y * 128;
  int half = m0g >= 4096;
  int m0 = m0g & 4095;
  int n0g = blockIdx.x * 128;
  int seg = n0g >> 10, n0 = n0g & 1023;

  const bf16* A = half ? hpb : hbb;
  const bf16* Wt = (seg == 0) ? wqT
                   : (seg == 1) ? (half ? wkSynT : wkSemT) : wvT;
  const float* bias = (seg == 0) ? bq
                      : (seg == 1) ? (half ? bk_syn : bk_sem) : bv;

  int w = tid >> 6, lane = tid & 63, quad = lane >> 4, ln = lane & 15;
  int wm = (w >> 1) * 64, wn = (w & 1) * 64;

  const f32x4 z = {0.f, 0.f, 0.f, 0.f};
  f32x4 acc[4][4];
#pragma unroll
  for (int i = 0; i < 4; i++)
#pragma unroll
    for (int j = 0; j < 4; j++) acc[i][j] = z;

  for (int k0 = 0; k0 < 1024; k0 += 32) {
    __syncthreads();
    stage128(Bs, Wt, n0, k0, 1024, tid);
    stage128(As, A, m0, k0, 1024, tid);
    __syncthreads();
    bf16x8 af[4], bfv[4];
#pragma unroll
    for (int mt = 0; mt < 4; mt++)
      af[mt] = *(bf16x8*)(As + (wm + mt * 16 + ln) * 32 + quad * 8);
#pragma unroll
    for (int nt = 0; nt < 4; nt++)
      bfv[nt] = *(bf16x8*)(Bs + (wn + nt * 16 + ln) * 32 + quad * 8);
#pragma unroll
    for (int mt = 0; mt < 4; mt++)
#pragma unroll
      for (int nt = 0; nt < 4; nt++)
        acc[mt][nt] = MFMA16(af[mt], bfv[nt], acc[mt][nt]);
  }

  if (seg == 2) {  // V: transposed store  vt[n][token]
    bf16* vt = half ? v0t : v1t;
#pragma unroll
    for (int nt = 0; nt < 4; nt++) {
      int n = n0 + wn + nt * 16 + ln;
      float bvv = bias[n];
#pragma unroll
      for (int mt = 0; mt < 4; mt++) {
        int mb = m0 + wm + mt * 16 + quad * 4;
        bf16x4 pk;
#pragma unroll
        for (int r = 0; r < 4; r++) pk[r] = (bf16)(acc[mt][nt][r] + bvv);
        *(bf16x4*)(vt + (size_t)n * 4096 + mb) = pk;
      }
    }
    return;
  }
  const float scale = (seg == 0) ? 0.1803368801f : 1.f;  // log2(e)/8 for Q
  bf16* out = (seg == 0) ? (half ? q1 : q0) : (half ? k0b : k1b);
#pragma unroll
  for (int nt = 0; nt < 4; nt++) {
    int n = n0 + wn + nt * 16 + ln;
    float bvv = bias[n];
#pragma unroll
    for (int mt = 0; mt < 4; mt++) {
      int mb = m0 + wm + mt * 16 + quad * 4;
#pragma unroll
      for (int r = 0; r < 4; r++)
        out[(size_t)(mb + r) * 1024 + n] =
            (bf16)((acc[mt][nt][r] + bvv) * scale);
    }
  }
}

// ---------------------------------------------------------------------------
// Fused gate GEMM (both branches): M=8192 stacked, K=2048, N=1024.
// g = sigmoid([A0|A1] @ W + b); out = g*enh + (1-g)*orig + orig
// A staged from bf16 copies; epilogue orig read in f32 for accuracy.
// ---------------------------------------------------------------------------
__global__ __launch_bounds__(256) void gate_gemm(
    const bf16* __restrict__ hbb, const bf16* __restrict__ hpb,
    const float* __restrict__ h_b, const float* __restrict__ h_p,
    const bf16* __restrict__ e0, const bf16* __restrict__ e1,
    const bf16* __restrict__ gSemT, const bf16* __restrict__ gSynT,
    const float* __restrict__ g_sem_b, const float* __restrict__ g_syn_b,
    bf16* __restrict__ ln0, bf16* __restrict__ ln1) {
  __shared__ bf16 As[128 * 32];
  __shared__ bf16 Bs[128 * 32];
  int tid = threadIdx.x;
  int m0g = blockIdx.y * 128;
  int half = m0g >= 4096;
  int m0 = m0g & 4095;
  int n0 = blockIdx.x * 128;

  const bf16* A0 = half ? hpb : hbb;
  const float* O0 = half ? h_p : h_b;
  const bf16* A1 = half ? e1 : e0;
  const bf16* Wt = half ? gSynT : gSemT;
  const float* bias = half ? g_syn_b : g_sem_b;
  bf16* out = half ? ln1 : ln0;

  int w = tid >> 6, lane = tid & 63, quad = lane >> 4, ln = lane & 15;
  int wm = (w >> 1) * 64, wn = (w & 1) * 64;

  const f32x4 z = {0.f, 0.f, 0.f, 0.f};
  f32x4 acc[4][4];
#pragma unroll
  for (int i = 0; i < 4; i++)
#pragma unroll
    for (int j = 0; j < 4; j++) acc[i][j] = z;

  for (int k0 = 0; k0 < 2048; k0 += 32) {
    __syncthreads();
    stage128(Bs, Wt, n0, k0, 2048, tid);
    if (k0 < 1024)
      stage128(As, A0, m0, k0, 1024, tid);
    else
      stage128(As, A1, m0, k0 - 1024, 1024, tid);
    __syncthreads();
    bf16x8 af[4], bfv[4];
#pragma unroll
    for (int mt = 0; mt < 4; mt++)
      af[mt] = *(bf16x8*)(As + (wm + mt * 16 + ln) * 32 + quad * 8);
#pragma unroll
    for (int nt = 0; nt < 4; nt++)
      bfv[nt] = *(bf16x8*)(Bs + (wn + nt * 16 + ln) * 32 + quad * 8);
#pragma unroll
    for (int mt = 0; mt < 4; mt++)
#pragma unroll
      for (int nt = 0; nt < 4; nt++)
        acc[mt][nt] = MFMA16(af[mt], bfv[nt], acc[mt][nt]);
  }

#pragma unroll
  for (int nt = 0; nt < 4; nt++) {
    int n = n0 + wn + nt * 16 + ln;
    float bvv = bias[n];
#pragma unroll
    for (int mt = 0; mt < 4; mt++) {
      int mb = m0 + wm + mt * 16 + quad * 4;
#pragma unroll
      for (int r = 0; r < 4; r++) {
        size_t idx = (size_t)(mb + r) * 1024 + n;
        float v = acc[mt][nt][r] + bvv;
        float e = (float)A1[idx], o = O0[idx];
        float g = 1.f / (1.f + __expf(-v));
        out[idx] = (bf16)(g * e + (1.f - g) * o + o);
      }
    }
  }
}

// ---------------------------------------------------------------------------
// fg1 GEMM: relu(cat[hbp,hpp] @ fg1_w + b). M=4096,K=2048,N=1024.
// 64x128 tile (grid 8x64 = 512 blocks) for co-residency at small M.
// ---------------------------------------------------------------------------
__global__ __launch_bounds__(256) void fg1_gemm(
    const bf16* __restrict__ A0, const bf16* __restrict__ A1,
    const bf16* __restrict__ Wt, const float* __restrict__ bias,
    bf16* __restrict__ out) {
  __shared__ bf16 As[64 * 32];
  __shared__ bf16 Bs[128 * 32];
  int tid = threadIdx.x;
  int m0 = blockIdx.y * 64, n0 = blockIdx.x * 128;
  int w = tid >> 6, lane = tid & 63, quad = lane >> 4, ln = lane & 15;
  int wm = (w >> 1) * 32, wn = (w & 1) * 64;

  const f32x4 z = {0.f, 0.f, 0.f, 0.f};
  f32x4 acc[2][4];
#pragma unroll
  for (int i = 0; i < 2; i++)
#pragma unroll
    for (int j = 0; j < 4; j++) acc[i][j] = z;

  for (int k0 = 0; k0 < 2048; k0 += 32) {
    __syncthreads();
    stage128(Bs, Wt, n0, k0, 2048, tid);
    if (k0 < 1024)
      stage64(As, A0, m0, k0, 1024, tid);
    else
      stage64(As, A1, m0, k0 - 1024, 1024, tid);
    __syncthreads();
    bf16x8 af[2], bfv[4];
#pragma unroll
    for (int mt = 0; mt < 2; mt++)
      af[mt] = *(bf16x8*)(As + (wm + mt * 16 + ln) * 32 + quad * 8);
#pragma unroll
    for (int nt = 0; nt < 4; nt++)
      bfv[nt] = *(bf16x8*)(Bs + (wn + nt * 16 + ln) * 32 + quad * 8);
#pragma unroll
    for (int mt = 0; mt < 2; mt++)
#pragma unroll
      for (int nt = 0; nt < 4; nt++)
        acc[mt][nt] = MFMA16(af[mt], bfv[nt], acc[mt][nt]);
  }

#pragma unroll
  for (int nt = 0; nt < 4; nt++) {
    int n = n0 + wn + nt * 16 + ln;
    float bvv = bias[n];
#pragma unroll
    for (int mt = 0; mt < 2; mt++) {
      int mb = m0 + wm + mt * 16 + quad * 4;
#pragma unroll
      for (int r = 0; r < 4; r++)
        out[(size_t)(mb + r) * 1024 + n] =
            (bf16)fmaxf(acc[mt][nt][r] + bvv, 0.f);
    }
  }
}

// ---------------------------------------------------------------------------
// Fused flash attention, both branches, S^T orientation (unchanged from R6).
// ---------------------------------------------------------------------------
__global__ __launch_bounds__(256) void attn_k(
    const bf16* __restrict__ q0, const bf16* __restrict__ q1,
    const bf16* __restrict__ k0b, const bf16* __restrict__ k1b,
    const bf16* __restrict__ v0t, const bf16* __restrict__ v1t,
    bf16* __restrict__ e0, bf16* __restrict__ e1) {
  int x = blockIdx.x;
  int branch = (x >> 3) & 1;
  int bh = (x & 7) * 8 + ((x >> 4) & 7);
  int qblk = x >> 7;
  int h = bh & 15, b = bh >> 4;
  const bf16* Q = branch ? q1 : q0;
  const bf16* Kp = branch ? k1b : k0b;
  const bf16* Vg = branch ? v1t : v0t;
  bf16* O = branch ? e1 : e0;
  size_t kbase = ((size_t)b * 1024) * 1024 + h * 64;
  size_t vbase = (size_t)h * 64 * 4096 + b * 1024;

  __shared__ bf16 Kt[2 * 64 * 32];    // [dhalf][k][32]
  __shared__ bf16 Vt[2 * 64 * 32];    // [khalf][d][32]
  __shared__ bf16 Pw[4][2 * 16 * 32]; // per wave: [khalf][q][32]

  int tid = threadIdx.x, w = tid >> 6, lane = tid & 63;
  int quad = lane >> 4, ln = lane & 15;
  int wq0 = qblk * 64 + w * 16;

  bf16x8 qf0 = *(const bf16x8*)(Q + kbase + (size_t)(wq0 + ln) * 1024 + quad * 8);
  bf16x8 qf1 =
      *(const bf16x8*)(Q + kbase + (size_t)(wq0 + ln) * 1024 + 32 + quad * 8);

  const f32x4 z = {0.f, 0.f, 0.f, 0.f};
  f32x4 oacc[4];
#pragma unroll
  for (int i = 0; i < 4; i++) oacc[i] = z;
  float m_run = -1e30f, l_run = 0.f;

  for (int kv0 = 0; kv0 < 1024; kv0 += 64) {
    __syncthreads();
#pragma unroll
    for (int i = 0; i < 2; i++) {
      int s = tid + i * 256;  // half=s>>8, row=(s>>2)&63, ch=s&3
      size_t wb = (size_t)(i * 256 + (tid & ~63)) * 8;
      async16(Kp + kbase + (size_t)(kv0 + ((s >> 2) & 63)) * 1024 +
                  (s >> 8) * 32 + (s & 3) * 8,
              Kt + wb);
      async16(Vg + vbase + (size_t)((s >> 2) & 63) * 4096 + kv0 +
                  (s >> 8) * 32 + (s & 3) * 8,
              Vt + wb);
    }
    __syncthreads();

    f32x4 s[4];
#pragma unroll
    for (int nt = 0; nt < 4; nt++) {
      bf16x8 kf0 = *(bf16x8*)(Kt + (nt * 16 + ln) * 32 + quad * 8);
      bf16x8 kf1 = *(bf16x8*)(Kt + 2048 + (nt * 16 + ln) * 32 + quad * 8);
      f32x4 a = z;
      a = MFMA16(kf0, qf0, a);
      a = MFMA16(kf1, qf1, a);
      s[nt] = a;
    }

    float mx = s[0][0];
#pragma unroll
    for (int nt = 0; nt < 4; nt++)
#pragma unroll
      for (int r = 0; r < 4; r++) mx = fmaxf(mx, s[nt][r]);
    mx = fmaxf(mx, __shfl_xor(mx, 16, 64));
    mx = fmaxf(mx, __shfl_xor(mx, 32, 64));

    float mn = fmaxf(m_run, mx);
    float alpha = EXP2(m_run - mn);
    m_run = mn;

    float rs = 0.f;
#pragma unroll
    for (int nt = 0; nt < 4; nt++)
#pragma unroll
      for (int r = 0; r < 4; r++) {
        float p = EXP2(s[nt][r] - mn);
        s[nt][r] = p;
        rs += p;
      }
    rs += __shfl_xor(rs, 16, 64);
    rs += __shfl_xor(rs, 32, 64);
    l_run = l_run * alpha + rs;

    float a_r[4];
#pragma unroll
    for (int r = 0; r < 4; r++) a_r[r] = __shfl(alpha, quad * 4 + r, 16);
#pragma unroll
    for (int dt = 0; dt < 4; dt++)
#pragma unroll
      for (int r = 0; r < 4; r++) oacc[dt][r] *= a_r[r];

#pragma unroll
    for (int nt = 0; nt < 4; nt++) {
      bf16x4 pk;
#pragma unroll
      for (int r = 0; r < 4; r++) pk[r] = (bf16)s[nt][r];
      *(bf16x4*)(Pw[w] + (nt >> 1) * 512 + ln * 32 + (nt & 1) * 16 + quad * 4) =
          pk;
    }

    bf16x8 pa0 = *(bf16x8*)(Pw[w] + ln * 32 + quad * 8);
    bf16x8 pa1 = *(bf16x8*)(Pw[w] + 512 + ln * 32 + quad * 8);
#pragma unroll
    for (int dt = 0; dt < 4; dt++) {
      bf16x8 vb0 = *(bf16x8*)(Vt + (dt * 16 + ln) * 32 + quad * 8);
      bf16x8 vb1 = *(bf16x8*)(Vt + 2048 + (dt * 16 + ln) * 32 + quad * 8);
      oacc[dt] = MFMA16(pa0, vb0, oacc[dt]);
      oacc[dt] = MFMA16(pa1, vb1, oacc[dt]);
    }
  }

  float l_r[4];
#pragma unroll
  for (int r = 0; r < 4; r++)
    l_r[r] = 1.f / __shfl(l_run, quad * 4 + r, 16);
#pragma unroll
  for (int dt = 0; dt < 4; dt++)
#pragma unroll
    for (int r = 0; r < 4; r++) {
      int q = wq0 + quad * 4 + r;
      O[kbase + (size_t)q * 1024 + dt * 16 + ln] =
          (bf16)(oacc[dt][r] * l_r[r]);
    }
}

// ---------------------------------------------------------------------------
// Merged LayerNorm (both branches), D=1024, one block per row. grid 8192.
// ---------------------------------------------------------------------------
__global__ __launch_bounds__(256) void ln_k(
    const bf16* __restrict__ x0, const bf16* __restrict__ x1,
    const float* __restrict__ g0, const float* __restrict__ b0,
    const float* __restrict__ g1, const float* __restrict__ b1,
    bf16* __restrict__ y0, bf16* __restrict__ y1) {
  int rowg = blockIdx.x, tid = threadIdx.x, c = tid * 4;
  int half = rowg >= 4096;
  int row = rowg & 4095;
  const bf16* x = half ? x1 : x0;
  const float* gg = half ? g1 : g0;
  const float* bb = half ? b1 : b0;
  bf16* y = half ? y1 : y0;

  bf16x4 x4 = *(const bf16x4*)(x + (size_t)row * 1024 + c);
  float v[4], s = 0.f, ss = 0.f;
#pragma unroll
  for (int i = 0; i < 4; i++) {
    v[i] = (float)x4[i];
    s += v[i];
    ss += v[i] * v[i];
  }
#pragma unroll
  for (int o = 32; o > 0; o >>= 1) {
    s += __shfl_down(s, o, 64);
    ss += __shfl_down(ss, o, 64);
  }
  __shared__ float red[8];
  int w = tid >> 6;
  if ((tid & 63) == 0) { red[w] = s; red[4 + w] = ss; }
  __syncthreads();
  s = red[0] + red[1] + red[2] + red[3];
  ss = red[4] + red[5] + red[6] + red[7];
  float mu = s * (1.f / 1024.f);
  float var = ss * (1.f / 1024.f) - mu * mu;
  float rstd = rsqrtf(var + 1e-5f);
  f32x4 g4 = *(const f32x4*)(gg + c), b4 = *(const f32x4*)(bb + c);
  bf16x4 o4;
#pragma unroll
  for (int i = 0; i < 4; i++) o4[i] = (bf16)((v[i] - mu) * rstd * g4[i] + b4[i]);
  *(bf16x4*)(y + (size_t)row * 1024 + c) = o4;
}

// ---------------------------------------------------------------------------
// fw = sigmoid(t . w2 + b2); out = fw*hbp + (1-fw)*hpp  (block per row)
// ---------------------------------------------------------------------------
__global__ __launch_bounds__(256) void fg2mix_k(const bf16* __restrict__ t,
                                                const float* __restrict__ w2,
                                                const float* __restrict__ b2,
                                                const bf16* __restrict__ hbp,
                                                const bf16* __restrict__ hpp,
                                                float* __restrict__ out) {
  int row = blockIdx.x, tid = threadIdx.x, c = tid * 4;
  bf16x4 t4 = *(const bf16x4*)(t + (size_t)row * 1024 + c);
  f32x4 w4 = *(const f32x4*)(w2 + c);
  float s = 0.f;
#pragma unroll
  for (int i = 0; i < 4; i++) s += (float)t4[i] * w4[i];
#pragma unroll
  for (int o = 32; o > 0; o >>= 1) s += __shfl_down(s, o, 64);
  __shared__ float red[4];
  if ((tid & 63) == 0) red[tid >> 6] = s;
  __syncthreads();
  s = red[0] + red[1] + red[2] + red[3];
  float fw = 1.f / (1.f + __expf(-(s + b2[0])));
  bf16x4 a4 = *(const bf16x4*)(hbp + (size_t)row * 1024 + c);
  bf16x4 p4 = *(const bf16x4*)(hpp + (size_t)row * 1024 + c);
  f32x4 o4;
#pragma unroll
  for (int i = 0; i < 4; i++)
    o4[i] = fw * (float)a4[i] + (1.f - fw) * (float)p4[i];
  *(f32x4*)(out + (size_t)row * 1024 + c) = o4;
}

// ---------------------------------------------------------------------------
extern "C" void kernel_launch(void* const* d_in, const int* in_sizes, int n_in,
                              void* d_out, int out_size, void* d_ws,
                              size_t ws_size, hipStream_t stream) {
  const float* h_b     = (const float*)d_in[0];
  const float* h_p     = (const float*)d_in[1];
  const float* wq      = (const float*)d_in[2];
  const float* bq      = (const float*)d_in[3];
  const float* wk_sem  = (const float*)d_in[4];
  const float* bk_sem  = (const float*)d_in[5];
  const float* wk_syn  = (const float*)d_in[6];
  const float* bk_syn  = (const float*)d_in[7];
  const float* wv      = (const float*)d_in[8];
  const float* bv      = (const float*)d_in[9];
  const float* g_sem_b = (const float*)d_in[11];
  const float* g_sem_w = (const float*)d_in[10];
  const float* g_syn_w = (const float*)d_in[12];
  const float* g_syn_b = (const float*)d_in[13];
  const float* ln_sem_g = (const float*)d_in[14];
  const float* ln_sem_b = (const float*)d_in[15];
  const float* ln_syn_g = (const float*)d_in[16];
  const float* ln_syn_b = (const float*)d_in[17];
  const float* fg1_w   = (const float*)d_in[18];
  const float* fg1_b   = (const float*)d_in[19];
  const float* fg2_w   = (const float*)d_in[20];
  const float* fg2_b   = (const float*)d_in[21];

  // workspace: 42M bf16 = 84 MB
  bf16* ws = (bf16*)d_ws;
  const size_t M1 = 1024ull * 1024ull;
  bf16* wqT    = ws + 0 * M1;   // [1024][1024]
  bf16* wkSemT = ws + 1 * M1;
  bf16* wkSynT = ws + 2 * M1;
  bf16* wvT    = ws + 3 * M1;
  bf16* gSemT  = ws + 4 * M1;   // [1024][2048]
  bf16* gSynT  = ws + 6 * M1;
  bf16* fg1T   = ws + 8 * M1;
  bf16* q0  = ws + 10 * M1;  // [4096][1024]
  bf16* q1  = ws + 14 * M1;
  bf16* k0b = ws + 18 * M1;
  bf16* k1b = ws + 22 * M1;
  bf16* v0t = ws + 26 * M1;  // [1024][4096]
  bf16* v1t = ws + 30 * M1;
  bf16* e0b = ws + 34 * M1;
  bf16* e1b = ws + 38 * M1;
  // bf16 copies of h_b/h_p live in d_out (16.8 MB; overwritten at the end)
  bf16* hbb = (bf16*)d_out;
  bf16* hpb = hbb + 4 * M1;
  // aliases over dead buffers
  bf16* ln0 = q0;   // after attn, q dead
  bf16* ln1 = q1;
  bf16* hbp = k0b;  // after gate gemm, k dead
  bf16* hpp = k1b;
  bf16* tb  = v0t;

  // 7 weight transposes + h_b/h_p bf16 conversion, one dispatch
  prep_k<<<14336, 256, 0, stream>>>(wq, wk_sem, wk_syn, wv, g_sem_w, g_syn_w,
                                    fg1_w, h_b, h_p, wqT, wkSemT, wkSynT, wvT,
                                    gSemT, gSynT, fg1T, hbb, hpb);

  // all 6 projections in one dispatch (1536 blocks)
  proj_gemm<<<dim3(24, 64), 256, 0, stream>>>(
      hbb, hpb, wqT, wkSemT, wkSynT, wvT, bq, bk_sem, bk_syn, bv,
      q0, q1, k0b, k1b, v0t, v1t);

  // both attention branches in one dispatch (2048 blocks)
  attn_k<<<2048, 256, 0, stream>>>(q0, q1, k0b, k1b, v0t, v1t, e0b, e1b);

  // both gate fusions in one dispatch (512 blocks)
  gate_gemm<<<dim3(8, 64), 256, 0, stream>>>(
      hbb, hpb, h_b, h_p, e0b, e1b, gSemT, gSynT, g_sem_b, g_syn_b, ln0, ln1);

  // both layernorms (8192 blocks)
  ln_k<<<8192, 256, 0, stream>>>(ln0, ln1, ln_sem_g, ln_sem_b, ln_syn_g,
                                 ln_syn_b, hbp, hpp);

  // fg1: relu(cat[hbp,hpp] @ fg1_w + b), 64x128 tiles (512 blocks)
  fg1_gemm<<<dim3(8, 64), 256, 0, stream>>>(hbp, hpp, fg1T, fg1_b, tb);

  fg2mix_k<<<4096, 256, 0, stream>>>(tb, fg2_w, fg2_b, hbp, hpp,
                                     (float*)d_out);
}